// Round 2
// baseline (5446.727 us; speedup 1.0000x reference)
//
#include <hip/hip_runtime.h>

typedef unsigned short u16;

__device__ __forceinline__ float fast_exp(float x) { return __expf(x); }
__device__ __forceinline__ float fast_rcp(float x) { return __builtin_amdgcn_rcpf(x); }
__device__ __forceinline__ float fast_tanh(float x) {
  float e = fast_exp(2.0f * x);            // 1 - 2/(e^{2x}+1), saturates correctly
  return 1.0f - 2.0f * fast_rcp(e + 1.0f);
}
__device__ __forceinline__ float fast_sigmoid(float x) {
  return fast_rcp(1.0f + fast_exp(-x));
}
__device__ __forceinline__ float bf2f(u16 u) {
  return __uint_as_float(((unsigned)u) << 16);
}
__device__ __forceinline__ u16 f2bf(float x) {  // round-to-nearest-even
  unsigned u = __float_as_uint(x);
  return (u16)((u + 0x7fffu + ((u >> 16) & 1u)) >> 16);
}

// ---------------------------------------------------------------------------
// Pack Whh_f/Whh_b (768x256, rows=[r|z|n]) into P[dir][k][i]=ushort4{r,z,n,0} bf16.
__global__ __launch_bounds__(256)
void k_pack(const float* __restrict__ Wf, const float* __restrict__ Wb,
            ushort4* __restrict__ P)
{
  int idx = blockIdx.x * 256 + threadIdx.x;   // dir*65536 + k*256 + i
  int dir = idx >> 16;
  int k = (idx >> 8) & 255;
  int i = idx & 255;
  const float* Wh = dir ? Wb : Wf;
  ushort4 o;
  o.x = f2bf(Wh[(size_t)i * 256 + k]);
  o.y = f2bf(Wh[(size_t)(256 + i) * 256 + k]);
  o.z = f2bf(Wh[(size_t)(512 + i) * 256 + k]);
  o.w = 0;
  P[idx] = o;
}

// ---------------------------------------------------------------------------
// C = epilogue(A @ W^T + bias). Row maps: map==1 -> A row m maps to v row
// (m/Tc)*320 + t0 + m%Tc (chunked (b,t) rows of v); map==0 -> identity (chunk
// buffer). A split along k as [A1 (.,K1) | A2 (.,K-K1)]. W is (N,K).
// 128x128 tile, BK=16, 256 threads, 8x8 microtile.
// MODE 0: C = x + bias.  MODE 1: C = pg*sigmoid(x), pg=[E1|E2] per maps.
template<int MODE>
__global__ __launch_bounds__(256)
void k_gemm(const float* __restrict__ A1, int K1, int map1,
            const float* __restrict__ A2, int map2,
            const float* __restrict__ W,
            const float* __restrict__ bias,
            const float* __restrict__ E1, const float* __restrict__ E2,
            float* __restrict__ C, int N, int K, int Tc, int t0)
{
  __shared__ float As[16][128];
  __shared__ float Bs[16][128];
  const int tid = threadIdx.x;
  const int m0 = blockIdx.x * 128;
  const int n0 = blockIdx.y * 128;
  const int K2 = K - K1;
  const int q = tid & 3;

  const float* pA1[2];
  const float* pA2[2];
  const float* pW[2];
#pragma unroll
  for (int r = 0; r < 2; ++r) {
    int row = m0 + r * 64 + (tid >> 2);
    int ar1 = map1 ? ((row / Tc) * 320 + t0 + row % Tc) : row;
    pA1[r] = A1 + (size_t)ar1 * K1;
    if (A2) {
      int ar2 = map2 ? ((row / Tc) * 320 + t0 + row % Tc) : row;
      pA2[r] = A2 + (size_t)ar2 * K2;
    } else {
      pA2[r] = nullptr;
    }
    pW[r] = W + (size_t)(n0 + r * 64 + (tid >> 2)) * K;
  }

  float acc[8][8];
#pragma unroll
  for (int i = 0; i < 8; ++i)
#pragma unroll
    for (int j = 0; j < 8; ++j) acc[i][j] = 0.f;
  const int tm = (tid & 15) * 8;
  const int tn = (tid >> 4) * 8;

  for (int k0 = 0; k0 < K; k0 += 16) {
#pragma unroll
    for (int r = 0; r < 2; ++r) {
      int row = r * 64 + (tid >> 2);
      int kk = k0 + q * 4;
      const float* Ap = (kk < K1) ? (pA1[r] + kk) : (pA2[r] + (kk - K1));
      float4 x = *(const float4*)Ap;
      As[q * 4 + 0][row] = x.x;
      As[q * 4 + 1][row] = x.y;
      As[q * 4 + 2][row] = x.z;
      As[q * 4 + 3][row] = x.w;
      float4 y = *(const float4*)(pW[r] + k0 + q * 4);
      Bs[q * 4 + 0][row] = y.x;
      Bs[q * 4 + 1][row] = y.y;
      Bs[q * 4 + 2][row] = y.z;
      Bs[q * 4 + 3][row] = y.w;
    }
    __syncthreads();
#pragma unroll
    for (int k = 0; k < 16; ++k) {
      float a[8], b[8];
      *(float4*)&a[0] = *(const float4*)&As[k][tm];
      *(float4*)&a[4] = *(const float4*)&As[k][tm + 4];
      *(float4*)&b[0] = *(const float4*)&Bs[k][tn];
      *(float4*)&b[4] = *(const float4*)&Bs[k][tn + 4];
#pragma unroll
      for (int i = 0; i < 8; ++i)
#pragma unroll
        for (int j = 0; j < 8; ++j) acc[i][j] += a[i] * b[j];
    }
    __syncthreads();
  }
#pragma unroll
  for (int i = 0; i < 8; ++i) {
    int m = m0 + tm + i;
    int er1 = map1 ? ((m / Tc) * 320 + t0 + m % Tc) : m;   // row in v for E1
    float* Crow = C + (size_t)m * N + n0 + tn;
#pragma unroll
    for (int j = 0; j < 8; ++j) {
      int n = n0 + tn + j;
      float x = acc[i][j] + bias[n];
      if (MODE == 1) {
        float pg = (n < 512) ? E1[(size_t)er1 * 512 + n]
                             : E2[(size_t)m * 512 + (n - 512)];
        x = pg * fast_sigmoid(x);
      }
      Crow[j] = x;
    }
  }
}

// ---------------------------------------------------------------------------
// sc[b,tl,s] = sum_d v[b,t0+tl,d] * tanh(cwm[b,tl,d] + cm[b,s,d])
__global__ __launch_bounds__(256)
void k_scores(const float* __restrict__ v, const float* __restrict__ cwm,
              const float* __restrict__ cm, float* __restrict__ sc,
              int Tc, int t0)
{
  __shared__ float vs[32][68], fs[32][68], cs[32][68];
  const int b = blockIdx.x;
  const int tl0 = blockIdx.y * 32;
  const int s0 = blockIdx.z * 32;
  const int tid = threadIdx.x;
  const int tx = tid & 15, ty = tid >> 4;
  const float* srcV = v   + ((size_t)b * 320 + t0 + tl0) * 512;
  const float* srcF = cwm + ((size_t)b * Tc + tl0) * 512;
  const float* srcC = cm  + ((size_t)b * 320 + s0) * 512;
  float a00 = 0, a01 = 0, a10 = 0, a11 = 0;
  for (int d0 = 0; d0 < 512; d0 += 64) {
#pragma unroll
    for (int r = 0; r < 2; ++r) {
      int f = r * 256 + tid;       // 512 f4 per array: 32 rows x 16 f4
      int row = f >> 4, qq = f & 15;
      *(float4*)&vs[row][qq * 4] = *(const float4*)(srcV + (size_t)row * 512 + d0 + qq * 4);
      *(float4*)&fs[row][qq * 4] = *(const float4*)(srcF + (size_t)row * 512 + d0 + qq * 4);
      *(float4*)&cs[row][qq * 4] = *(const float4*)(srcC + (size_t)row * 512 + d0 + qq * 4);
    }
    __syncthreads();
#pragma unroll 4
    for (int d = 0; d < 64; ++d) {
      float c0 = cs[tx][d], c1 = cs[tx + 16][d];
      float v0 = vs[ty][d], v1 = vs[ty + 16][d];
      float w0 = fs[ty][d], w1 = fs[ty + 16][d];
      a00 += v0 * fast_tanh(w0 + c0);
      a01 += v0 * fast_tanh(w0 + c1);
      a10 += v1 * fast_tanh(w1 + c0);
      a11 += v1 * fast_tanh(w1 + c1);
    }
    __syncthreads();
  }
  float* o = sc + (size_t)b * Tc * 320;
  o[(size_t)(tl0 + ty) * 320 + s0 + tx]           = a00;
  o[(size_t)(tl0 + ty) * 320 + s0 + tx + 16]      = a01;
  o[(size_t)(tl0 + ty + 16) * 320 + s0 + tx]      = a10;
  o[(size_t)(tl0 + ty + 16) * 320 + s0 + tx + 16] = a11;
}

// ---------------------------------------------------------------------------
// In-place softmax over last dim (320). One wave per row; grid covers rows/4.
__global__ __launch_bounds__(256)
void k_softmax(float* __restrict__ sc)
{
  int wave = threadIdx.x >> 6;
  int lane = threadIdx.x & 63;
  int row = blockIdx.x * 4 + wave;
  float* p = sc + (size_t)row * 320;
  float x[5];
  float mx = -1e30f;
#pragma unroll
  for (int j = 0; j < 5; ++j) { x[j] = p[lane + 64 * j]; mx = fmaxf(mx, x[j]); }
#pragma unroll
  for (int off = 32; off > 0; off >>= 1) mx = fmaxf(mx, __shfl_xor(mx, off));
  float s = 0.f;
#pragma unroll
  for (int j = 0; j < 5; ++j) { x[j] = fast_exp(x[j] - mx); s += x[j]; }
#pragma unroll
  for (int off = 32; off > 0; off >>= 1) s += __shfl_xor(s, off);
  float rinv = fast_rcp(s);
#pragma unroll
  for (int j = 0; j < 5; ++j) p[lane + 64 * j] = x[j] * rinv;
}

// ---------------------------------------------------------------------------
// cell[b,tl,d] = sum_s attn[b,tl,s] * v[b,s,d].  32x64 tile (Tc multiple of 32).
__global__ __launch_bounds__(256)
void k_cell(const float* __restrict__ attn, const float* __restrict__ v,
            float* __restrict__ cell, int Tc)
{
  __shared__ float As[16][32], Bs[16][64];
  const int b = blockIdx.x;
  const int m0 = blockIdx.y * 32;
  const int n0 = blockIdx.z * 64;
  const int tid = threadIdx.x;
  const float* A = attn + (size_t)b * Tc * 320;
  const float* B = v + (size_t)b * 320 * 512;
  float acc[2][4];
#pragma unroll
  for (int i = 0; i < 2; ++i)
#pragma unroll
    for (int j = 0; j < 4; ++j) acc[i][j] = 0.f;
  const int tm = (tid & 15) * 2, tn = (tid >> 4) * 4;
  for (int k0 = 0; k0 < 320; k0 += 16) {
    if (tid < 128) {
      int row = tid >> 2, q = tid & 3;          // A: 32 rows x 4 f4
      float4 x = *(const float4*)(A + (size_t)(m0 + row) * 320 + k0 + q * 4);
      As[q * 4 + 0][row] = x.x;
      As[q * 4 + 1][row] = x.y;
      As[q * 4 + 2][row] = x.z;
      As[q * 4 + 3][row] = x.w;
    }
    {
      int krow = tid >> 4, qq = tid & 15;       // B: 16 k-rows x 16 f4
      *(float4*)&Bs[krow][qq * 4] =
          *(const float4*)(B + (size_t)(k0 + krow) * 512 + n0 + qq * 4);
    }
    __syncthreads();
#pragma unroll
    for (int k = 0; k < 16; ++k) {
      float a0 = As[k][tm], a1 = As[k][tm + 1];
      float bb[4];
      *(float4*)&bb[0] = *(const float4*)&Bs[k][tn];
#pragma unroll
      for (int j = 0; j < 4; ++j) { acc[0][j] += a0 * bb[j]; acc[1][j] += a1 * bb[j]; }
    }
    __syncthreads();
  }
#pragma unroll
  for (int i = 0; i < 2; ++i) {
    float4 o = make_float4(acc[i][0], acc[i][1], acc[i][2], acc[i][3]);
    *(float4*)(cell + ((size_t)b * Tc + m0 + tm + i) * 512 + n0 + tn) = o;
  }
}

// ---------------------------------------------------------------------------
// Sequential GRU over the chunk's Tc steps. One block per (b,dir); h carried
// across chunk launches in global hstate (same stream -> ordered).
__global__ __launch_bounds__(256)
void k_recur(const float* __restrict__ GIf, const float* __restrict__ GIb,
             const ushort4* __restrict__ P,
             const float* __restrict__ bhh_f, const float* __restrict__ bhh_b,
             float* __restrict__ out, float* __restrict__ hstate,
             int Tc, int t0, int init)
{
  const int b = blockIdx.x >> 1;
  const int dir = blockIdx.x & 1;
  const int i = threadIdx.x;
  __shared__ float hs[256];
  hs[i] = init ? 0.f : hstate[blockIdx.x * 256 + i];
  const float* GI = (dir ? GIb : GIf) + (size_t)b * Tc * 768;
  const float* bhh = dir ? bhh_b : bhh_f;
  const ushort4* Pd = P + (size_t)dir * 65536;
  const float br = bhh[i], bz = bhh[256 + i], bn = bhh[512 + i];
  float* op = out + (size_t)t0 * 32768 + (size_t)b * 512 + dir * 256 + i;
  __syncthreads();
  for (int t = 0; t < Tc; ++t) {
    const float* gi = GI + (size_t)t * 768;
    float gr = gi[i], gz = gi[256 + i], gn = gi[512 + i];
    float ar = 0.f, az = 0.f, an = 0.f;
#pragma unroll 2
    for (int k = 0; k < 256; k += 4) {
      float4 h4 = *(const float4*)&hs[k];      // wave-uniform broadcast
#pragma unroll
      for (int kk = 0; kk < 4; ++kk) {
        ushort4 wp = Pd[(k + kk) * 256 + i];   // coalesced 8B/lane, L2-resident
        float hk = (&h4.x)[kk];
        ar += bf2f(wp.x) * hk;
        az += bf2f(wp.y) * hk;
        an += bf2f(wp.z) * hk;
      }
    }
    float r = fast_sigmoid(gr + ar + br);
    float z = fast_sigmoid(gz + az + bz);
    float n = fast_tanh(gn + r * (an + bn));
    float hold = hs[i];
    float hnew = (1.f - z) * n + z * hold;
    __syncthreads();                           // all k-loop reads of hs done
    hs[i] = hnew;
    op[(size_t)t * 32768] = hnew;              // out[t0+t, b, dir*256+i]
    __syncthreads();
  }
  hstate[blockIdx.x * 256 + i] = hs[i];
}

// ---------------------------------------------------------------------------
extern "C" void kernel_launch(void* const* d_in, const int* in_sizes, int n_in,
                              void* d_out, int out_size, void* d_ws, size_t ws_size,
                              hipStream_t stream)
{
  const float* v     = (const float*)d_in[0];
  const float* W1    = (const float*)d_in[1];
  const float* b1    = (const float*)d_in[2];
  const float* W2    = (const float*)d_in[3];
  const float* b2    = (const float*)d_in[4];
  const float* Wg    = (const float*)d_in[5];
  const float* bg    = (const float*)d_in[6];
  const float* Wih_f = (const float*)d_in[7];
  const float* Whh_f = (const float*)d_in[8];
  const float* bih_f = (const float*)d_in[9];
  const float* bhh_f = (const float*)d_in[10];
  const float* Wih_b = (const float*)d_in[11];
  const float* Whh_b = (const float*)d_in[12];
  const float* bih_b = (const float*)d_in[13];
  const float* bhh_b = (const float*)d_in[14];
  float* out = (float*)d_out;
  float* w = (float*)d_ws;

  // Pick largest chunk that fits ws_size: bytes = 4*(10780672 + 249856*Tc).
  // Tc=320 -> 363 MB, 160 -> 203 MB, 64 -> 107 MB, 32 -> 75 MB.
  int Tc = 32;
  {
    const int cand[4] = {320, 160, 64, 32};
    for (int ci = 0; ci < 4; ++ci) {
      size_t need = 4ull * (10780672ull + 249856ull * (size_t)cand[ci]);
      if (need <= ws_size) { Tc = cand[ci]; break; }
    }
  }
  const int nc = 320 / Tc;

  // Workspace layout (floats)
  float* cm     = w;                                  // 10485760 (full, all chunks)
  float* hstate = w + 10485760;                       // 32768
  ushort4* P    = (ushort4*)(w + 10518528);           // 262144 floats (1 MB)
  float* cwm    = w + 10780672;                       // 32768*Tc
  float* attn   = cwm  + (size_t)32768 * Tc;          // 20480*Tc
  float* cell   = attn + (size_t)20480 * Tc;          // 32768*Tc
  float* gi     = cell + (size_t)32768 * Tc;          // 65536*Tc
  float* GIf    = gi   + (size_t)65536 * Tc;          // 49152*Tc
  float* GIb    = GIf  + (size_t)49152 * Tc;          // 49152*Tc

  k_pack<<<512, 256, 0, stream>>>(Whh_f, Whh_b, P);
  // cm = v@W2^T + b2  (full 20480 rows, identity v-map via Tc=320,t0=0)
  k_gemm<0><<<dim3(160, 4), 256, 0, stream>>>(v, 512, 1, nullptr, 0, W2, b2,
                                              nullptr, nullptr, cm, 512, 512, 320, 0);
  for (int c = 0; c < nc; ++c) {
    const int t0 = c * Tc;
    const int Mc = 64 * Tc;
    // cwm = v_chunk@W1^T + b1
    k_gemm<0><<<dim3(Mc / 128, 4), 256, 0, stream>>>(v, 512, 1, nullptr, 0, W1, b1,
                                                     nullptr, nullptr, cwm, 512, 512, Tc, t0);
    k_scores<<<dim3(64, Tc / 32, 10), 256, 0, stream>>>(v, cwm, cm, attn, Tc, t0);
    k_softmax<<<Mc / 4, 256, 0, stream>>>(attn);
    k_cell<<<dim3(64, Tc / 32, 8), 256, 0, stream>>>(attn, v, cell, Tc);
    // gi = pg * sigmoid(pg@Wg^T + bg), pg = [v_chunk | cell]
    k_gemm<1><<<dim3(Mc / 128, 8), 256, 0, stream>>>(v, 512, 1, cell, 0, Wg, bg,
                                                     v, cell, gi, 1024, 1024, Tc, t0);
    // GI_f/b = gi @ Wih^T + bih
    k_gemm<0><<<dim3(Mc / 128, 6), 256, 0, stream>>>(gi, 1024, 0, nullptr, 0, Wih_f, bih_f,
                                                     nullptr, nullptr, GIf, 768, 1024, Tc, t0);
    k_gemm<0><<<dim3(Mc / 128, 6), 256, 0, stream>>>(gi, 1024, 0, nullptr, 0, Wih_b, bih_b,
                                                     nullptr, nullptr, GIb, 768, 1024, Tc, t0);
    k_recur<<<128, 256, 0, stream>>>(GIf, GIb, P, bhh_f, bhh_b, out, hstate,
                                     Tc, t0, (c == 0) ? 1 : 0);
  }
}

// Round 4
// 3346.971 us; speedup vs baseline: 1.6274x; 1.6274x over previous
//
#include <hip/hip_runtime.h>

typedef unsigned short u16;
typedef __fp16 h2 __attribute__((ext_vector_type(2)));

__device__ __forceinline__ float fast_exp(float x) { return __expf(x); }
__device__ __forceinline__ float fast_rcp(float x) { return __builtin_amdgcn_rcpf(x); }
__device__ __forceinline__ float fast_tanh(float x) {
  float e = fast_exp(2.0f * x);            // 1 - 2/(e^{2x}+1), saturates correctly
  return 1.0f - 2.0f * fast_rcp(e + 1.0f);
}
__device__ __forceinline__ float fast_sigmoid(float x) {
  return fast_rcp(1.0f + fast_exp(-x));
}

// ---------------------------------------------------------------------------
// C = epilogue(A @ W^T + bias). Row maps: map==1 -> A row m maps to v row
// (m/Tc)*320 + t0 + m%Tc (chunked (b,t) rows of v); map==0 -> identity (chunk
// buffer). A split along k as [A1 (.,K1) | A2 (.,K-K1)]. W is (N,K).
// 128x128 tile, BK=16, 256 threads, 8x8 microtile.
// MODE 0: C = x + bias.  MODE 1: C = pg*sigmoid(x), pg=[E1|E2] per maps.
template<int MODE>
__global__ __launch_bounds__(256)
void k_gemm(const float* __restrict__ A1, int K1, int map1,
            const float* __restrict__ A2, int map2,
            const float* __restrict__ W,
            const float* __restrict__ bias,
            const float* __restrict__ E1, const float* __restrict__ E2,
            float* __restrict__ C, int N, int K, int Tc, int t0)
{
  __shared__ float As[16][128];
  __shared__ float Bs[16][128];
  const int tid = threadIdx.x;
  const int m0 = blockIdx.x * 128;
  const int n0 = blockIdx.y * 128;
  const int K2 = K - K1;
  const int q = tid & 3;

  const float* pA1[2];
  const float* pA2[2];
  const float* pW[2];
#pragma unroll
  for (int r = 0; r < 2; ++r) {
    int row = m0 + r * 64 + (tid >> 2);
    int ar1 = map1 ? ((row / Tc) * 320 + t0 + row % Tc) : row;
    pA1[r] = A1 + (size_t)ar1 * K1;
    if (A2) {
      int ar2 = map2 ? ((row / Tc) * 320 + t0 + row % Tc) : row;
      pA2[r] = A2 + (size_t)ar2 * K2;
    } else {
      pA2[r] = nullptr;
    }
    pW[r] = W + (size_t)(n0 + r * 64 + (tid >> 2)) * K;
  }

  float acc[8][8];
#pragma unroll
  for (int i = 0; i < 8; ++i)
#pragma unroll
    for (int j = 0; j < 8; ++j) acc[i][j] = 0.f;
  const int tm = (tid & 15) * 8;
  const int tn = (tid >> 4) * 8;

  for (int k0 = 0; k0 < K; k0 += 16) {
#pragma unroll
    for (int r = 0; r < 2; ++r) {
      int row = r * 64 + (tid >> 2);
      int kk = k0 + q * 4;
      const float* Ap = (kk < K1) ? (pA1[r] + kk) : (pA2[r] + (kk - K1));
      float4 x = *(const float4*)Ap;
      As[q * 4 + 0][row] = x.x;
      As[q * 4 + 1][row] = x.y;
      As[q * 4 + 2][row] = x.z;
      As[q * 4 + 3][row] = x.w;
      float4 y = *(const float4*)(pW[r] + k0 + q * 4);
      Bs[q * 4 + 0][row] = y.x;
      Bs[q * 4 + 1][row] = y.y;
      Bs[q * 4 + 2][row] = y.z;
      Bs[q * 4 + 3][row] = y.w;
    }
    __syncthreads();
#pragma unroll
    for (int k = 0; k < 16; ++k) {
      float a[8], b[8];
      *(float4*)&a[0] = *(const float4*)&As[k][tm];
      *(float4*)&a[4] = *(const float4*)&As[k][tm + 4];
      *(float4*)&b[0] = *(const float4*)&Bs[k][tn];
      *(float4*)&b[4] = *(const float4*)&Bs[k][tn + 4];
#pragma unroll
      for (int i = 0; i < 8; ++i)
#pragma unroll
        for (int j = 0; j < 8; ++j) acc[i][j] += a[i] * b[j];
    }
    __syncthreads();
  }
#pragma unroll
  for (int i = 0; i < 8; ++i) {
    int m = m0 + tm + i;
    int er1 = map1 ? ((m / Tc) * 320 + t0 + m % Tc) : m;   // row in v for E1
    float* Crow = C + (size_t)m * N + n0 + tn;
#pragma unroll
    for (int j = 0; j < 8; ++j) {
      int n = n0 + tn + j;
      float x = acc[i][j] + bias[n];
      if (MODE == 1) {
        float pg = (n < 512) ? E1[(size_t)er1 * 512 + n]
                             : E2[(size_t)m * 512 + (n - 512)];
        x = pg * fast_sigmoid(x);
      }
      Crow[j] = x;
    }
  }
}

// ---------------------------------------------------------------------------
// sc[b,tl,s] = sum_d v[b,t0+tl,d] * tanh(cwm[b,tl,d] + cm[b,s,d])
__global__ __launch_bounds__(256)
void k_scores(const float* __restrict__ v, const float* __restrict__ cwm,
              const float* __restrict__ cm, float* __restrict__ sc,
              int Tc, int t0)
{
  __shared__ float vs[32][68], fs[32][68], cs[32][68];
  const int b = blockIdx.x;
  const int tl0 = blockIdx.y * 32;
  const int s0 = blockIdx.z * 32;
  const int tid = threadIdx.x;
  const int tx = tid & 15, ty = tid >> 4;
  const float* srcV = v   + ((size_t)b * 320 + t0 + tl0) * 512;
  const float* srcF = cwm + ((size_t)b * Tc + tl0) * 512;
  const float* srcC = cm  + ((size_t)b * 320 + s0) * 512;
  float a00 = 0, a01 = 0, a10 = 0, a11 = 0;
  for (int d0 = 0; d0 < 512; d0 += 64) {
#pragma unroll
    for (int r = 0; r < 2; ++r) {
      int f = r * 256 + tid;       // 512 f4 per array: 32 rows x 16 f4
      int row = f >> 4, qq = f & 15;
      *(float4*)&vs[row][qq * 4] = *(const float4*)(srcV + (size_t)row * 512 + d0 + qq * 4);
      *(float4*)&fs[row][qq * 4] = *(const float4*)(srcF + (size_t)row * 512 + d0 + qq * 4);
      *(float4*)&cs[row][qq * 4] = *(const float4*)(srcC + (size_t)row * 512 + d0 + qq * 4);
    }
    __syncthreads();
#pragma unroll 4
    for (int d = 0; d < 64; ++d) {
      float c0 = cs[tx][d], c1 = cs[tx + 16][d];
      float v0 = vs[ty][d], v1 = vs[ty + 16][d];
      float w0 = fs[ty][d], w1 = fs[ty + 16][d];
      a00 += v0 * fast_tanh(w0 + c0);
      a01 += v0 * fast_tanh(w0 + c1);
      a10 += v1 * fast_tanh(w1 + c0);
      a11 += v1 * fast_tanh(w1 + c1);
    }
    __syncthreads();
  }
  float* o = sc + (size_t)b * Tc * 320;
  o[(size_t)(tl0 + ty) * 320 + s0 + tx]           = a00;
  o[(size_t)(tl0 + ty) * 320 + s0 + tx + 16]      = a01;
  o[(size_t)(tl0 + ty + 16) * 320 + s0 + tx]      = a10;
  o[(size_t)(tl0 + ty + 16) * 320 + s0 + tx + 16] = a11;
}

// ---------------------------------------------------------------------------
// In-place softmax over last dim (320). One wave per row; grid covers rows/4.
__global__ __launch_bounds__(256)
void k_softmax(float* __restrict__ sc)
{
  int wave = threadIdx.x >> 6;
  int lane = threadIdx.x & 63;
  int row = blockIdx.x * 4 + wave;
  float* p = sc + (size_t)row * 320;
  float x[5];
  float mx = -1e30f;
#pragma unroll
  for (int j = 0; j < 5; ++j) { x[j] = p[lane + 64 * j]; mx = fmaxf(mx, x[j]); }
#pragma unroll
  for (int off = 32; off > 0; off >>= 1) mx = fmaxf(mx, __shfl_xor(mx, off));
  float s = 0.f;
#pragma unroll
  for (int j = 0; j < 5; ++j) { x[j] = fast_exp(x[j] - mx); s += x[j]; }
#pragma unroll
  for (int off = 32; off > 0; off >>= 1) s += __shfl_xor(s, off);
  float rinv = fast_rcp(s);
#pragma unroll
  for (int j = 0; j < 5; ++j) p[lane + 64 * j] = x[j] * rinv;
}

// ---------------------------------------------------------------------------
// cell[b,tl,d] = sum_s attn[b,tl,s] * v[b,s,d].  32x64 tile (Tc multiple of 32).
__global__ __launch_bounds__(256)
void k_cell(const float* __restrict__ attn, const float* __restrict__ v,
            float* __restrict__ cell, int Tc)
{
  __shared__ float As[16][32], Bs[16][64];
  const int b = blockIdx.x;
  const int m0 = blockIdx.y * 32;
  const int n0 = blockIdx.z * 64;
  const int tid = threadIdx.x;
  const float* A = attn + (size_t)b * Tc * 320;
  const float* B = v + (size_t)b * 320 * 512;
  float acc[2][4];
#pragma unroll
  for (int i = 0; i < 2; ++i)
#pragma unroll
    for (int j = 0; j < 4; ++j) acc[i][j] = 0.f;
  const int tm = (tid & 15) * 2, tn = (tid >> 4) * 4;
  for (int k0 = 0; k0 < 320; k0 += 16) {
    if (tid < 128) {
      int row = tid >> 2, q = tid & 3;          // A: 32 rows x 4 f4
      float4 x = *(const float4*)(A + (size_t)(m0 + row) * 320 + k0 + q * 4);
      As[q * 4 + 0][row] = x.x;
      As[q * 4 + 1][row] = x.y;
      As[q * 4 + 2][row] = x.z;
      As[q * 4 + 3][row] = x.w;
    }
    {
      int krow = tid >> 4, qq = tid & 15;       // B: 16 k-rows x 16 f4
      *(float4*)&Bs[krow][qq * 4] =
          *(const float4*)(B + (size_t)(k0 + krow) * 512 + n0 + qq * 4);
    }
    __syncthreads();
#pragma unroll
    for (int k = 0; k < 16; ++k) {
      float a0 = As[k][tm], a1 = As[k][tm + 1];
      float bb[4];
      *(float4*)&bb[0] = *(const float4*)&Bs[k][tn];
#pragma unroll
      for (int j = 0; j < 4; ++j) { acc[0][j] += a0 * bb[j]; acc[1][j] += a1 * bb[j]; }
    }
    __syncthreads();
  }
#pragma unroll
  for (int i = 0; i < 2; ++i) {
    float4 o = make_float4(acc[i][0], acc[i][1], acc[i][2], acc[i][3]);
    *(float4*)(cell + ((size_t)b * Tc + m0 + tm + i) * 512 + n0 + tn) = o;
  }
}

// ---------------------------------------------------------------------------
// Sequential GRU over the chunk's Tc steps. One block per (b,dir), 512 threads:
// thread = (i = tid&255, half = tid>>8). Whh rows for this thread's i are held
// as packed-f16 pairs IN REGISTERS (192 VGPRs) -- zero per-step weight traffic
// (round-2 k_recur was per-CU L2-BW-bound re-reading 512KB/step). Per step, h
// is round-tripped through 512B of LDS in f16; each lane grabs all of h with
// one ds_read_b64, then pairs are broadcast via v_readlane and accumulated with
// v_dot2_f32_f16. h carried across chunk launches in global hstate.
__global__ __launch_bounds__(512)
void k_recur(const float* __restrict__ GIf, const float* __restrict__ GIb,
             const float* __restrict__ Whh_f, const float* __restrict__ Whh_b,
             const float* __restrict__ bhh_f, const float* __restrict__ bhh_b,
             float* __restrict__ out, float* __restrict__ hstate,
             int Tc, int t0, int init)
{
  const int b = blockIdx.x >> 1;
  const int dir = blockIdx.x & 1;
  const int tid = threadIdx.x;
  const int i = tid & 255;
  const int half = __builtin_amdgcn_readfirstlane(tid >> 8);  // wave-uniform
  const int lane = tid & 63;

  __shared__ float part[3][256];          // half1 partial acc (r,z,n)
  __shared__ alignas(8) __fp16 hh16[256];

  const float* Wh  = dir ? Whh_b : Whh_f;
  const float* bhh = dir ? bhh_b : bhh_f;
  const float* GI  = (dir ? GIb : GIf) + (size_t)b * Tc * 768;

  // ---- load this thread's weight slice into registers (f16 pairs) ----
  h2 wr[64], wz[64], wn[64];
  {
    const float* Wr = Wh + (size_t)i * 256 + half * 128;
    const float* Wz = Wh + (size_t)(256 + i) * 256 + half * 128;
    const float* Wn = Wh + (size_t)(512 + i) * 256 + half * 128;
#pragma unroll
    for (int qd = 0; qd < 32; ++qd) {
      float4 x = *(const float4*)(Wr + 4 * qd);
      wr[2 * qd]     = __builtin_amdgcn_cvt_pkrtz(x.x, x.y);
      wr[2 * qd + 1] = __builtin_amdgcn_cvt_pkrtz(x.z, x.w);
      float4 y = *(const float4*)(Wz + 4 * qd);
      wz[2 * qd]     = __builtin_amdgcn_cvt_pkrtz(y.x, y.y);
      wz[2 * qd + 1] = __builtin_amdgcn_cvt_pkrtz(y.z, y.w);
      float4 zv = *(const float4*)(Wn + 4 * qd);
      wn[2 * qd]     = __builtin_amdgcn_cvt_pkrtz(zv.x, zv.y);
      wn[2 * qd + 1] = __builtin_amdgcn_cvt_pkrtz(zv.z, zv.w);
    }
  }

  float br = 0.f, bz = 0.f, bn = 0.f, hown = 0.f;
  if (half == 0) {
    br = bhh[i]; bz = bhh[256 + i]; bn = bhh[512 + i];
    hown = init ? 0.f : hstate[(size_t)blockIdx.x * 256 + i];
    hh16[i] = (__fp16)hown;
  }
  float* op = out + (size_t)t0 * 32768 + (size_t)b * 512 + dir * 256 + i;
  __syncthreads();

  // distributed h: lane L holds halves 4L..4L+3 as two packed pairs
  int2 hp = *(const int2*)((const char*)hh16 + 8 * lane);

  for (int t = 0; t < Tc; ++t) {
    const float* gi = GI + (size_t)t * 768;
    float gr = 0.f, gz = 0.f, gn = 0.f;
    if (half == 0) { gr = gi[i]; gz = gi[256 + i]; gn = gi[512 + i]; }

    float ar = 0.f, az = 0.f, an = 0.f;
    const int lbase = half * 32;
#pragma unroll
    for (int p = 0; p < 64; ++p) {
      int src = (p & 1) ? hp.y : hp.x;
      h2 hh = __builtin_bit_cast(h2, __builtin_amdgcn_readlane(src, lbase + (p >> 1)));
      ar = __builtin_amdgcn_fdot2(wr[p], hh, ar, false);
      az = __builtin_amdgcn_fdot2(wz[p], hh, az, false);
      an = __builtin_amdgcn_fdot2(wn[p], hh, an, false);
    }
    if (half == 1) {
      part[0][i] = ar; part[1][i] = az; part[2][i] = an;
    }
    __syncthreads();                       // A: partials visible
    if (half == 0) {
      float r  = fast_sigmoid(gr + ar + part[0][i] + br);
      float z  = fast_sigmoid(gz + az + part[1][i] + bz);
      float nn = fast_tanh(gn + r * (an + part[2][i] + bn));
      hown = (1.f - z) * nn + z * hown;
      op[(size_t)t * 32768] = hown;        // out[t0+t, b, dir*256+i]
      hh16[i] = (__fp16)hown;
    }
    __syncthreads();                       // B: new h visible
    hp = *(const int2*)((const char*)hh16 + 8 * lane);
  }
  if (half == 0) hstate[(size_t)blockIdx.x * 256 + i] = hown;
}

// ---------------------------------------------------------------------------
extern "C" void kernel_launch(void* const* d_in, const int* in_sizes, int n_in,
                              void* d_out, int out_size, void* d_ws, size_t ws_size,
                              hipStream_t stream)
{
  const float* v     = (const float*)d_in[0];
  const float* W1    = (const float*)d_in[1];
  const float* b1    = (const float*)d_in[2];
  const float* W2    = (const float*)d_in[3];
  const float* b2    = (const float*)d_in[4];
  const float* Wg    = (const float*)d_in[5];
  const float* bg    = (const float*)d_in[6];
  const float* Wih_f = (const float*)d_in[7];
  const float* Whh_f = (const float*)d_in[8];
  const float* bih_f = (const float*)d_in[9];
  const float* bhh_f = (const float*)d_in[10];
  const float* Wih_b = (const float*)d_in[11];
  const float* Whh_b = (const float*)d_in[12];
  const float* bih_b = (const float*)d_in[13];
  const float* bhh_b = (const float*)d_in[14];
  float* out = (float*)d_out;
  float* w = (float*)d_ws;

  // Pick largest chunk that fits ws_size: bytes = 4*(10780672 + 249856*Tc).
  int Tc = 32;
  {
    const int cand[4] = {320, 160, 64, 32};
    for (int ci = 0; ci < 4; ++ci) {
      size_t need = 4ull * (10780672ull + 249856ull * (size_t)cand[ci]);
      if (need <= ws_size) { Tc = cand[ci]; break; }
    }
  }
  const int nc = 320 / Tc;

  // Workspace layout (floats)
  float* cm     = w;                                  // 10485760 (full, all chunks)
  float* hstate = w + 10485760;                       // 32768
  float* cwm    = w + 10780672;                       // 32768*Tc
  float* attn   = cwm  + (size_t)32768 * Tc;          // 20480*Tc
  float* cell   = attn + (size_t)20480 * Tc;          // 32768*Tc
  float* gi     = cell + (size_t)32768 * Tc;          // 65536*Tc
  float* GIf    = gi   + (size_t)65536 * Tc;          // 49152*Tc
  float* GIb    = GIf  + (size_t)49152 * Tc;          // 49152*Tc

  // cm = v@W2^T + b2  (full 20480 rows, identity v-map via Tc=320,t0=0)
  k_gemm<0><<<dim3(160, 4), 256, 0, stream>>>(v, 512, 1, nullptr, 0, W2, b2,
                                              nullptr, nullptr, cm, 512, 512, 320, 0);
  for (int c = 0; c < nc; ++c) {
    const int t0 = c * Tc;
    const int Mc = 64 * Tc;
    // cwm = v_chunk@W1^T + b1
    k_gemm<0><<<dim3(Mc / 128, 4), 256, 0, stream>>>(v, 512, 1, nullptr, 0, W1, b1,
                                                     nullptr, nullptr, cwm, 512, 512, Tc, t0);
    k_scores<<<dim3(64, Tc / 32, 10), 256, 0, stream>>>(v, cwm, cm, attn, Tc, t0);
    k_softmax<<<Mc / 4, 256, 0, stream>>>(attn);
    k_cell<<<dim3(64, Tc / 32, 8), 256, 0, stream>>>(attn, v, cell, Tc);
    // gi = pg * sigmoid(pg@Wg^T + bg), pg = [v_chunk | cell]
    k_gemm<1><<<dim3(Mc / 128, 8), 256, 0, stream>>>(v, 512, 1, cell, 0, Wg, bg,
                                                     v, cell, gi, 1024, 1024, Tc, t0);
    // GI_f/b = gi @ Wih^T + bih
    k_gemm<0><<<dim3(Mc / 128, 6), 256, 0, stream>>>(gi, 1024, 0, nullptr, 0, Wih_f, bih_f,
                                                     nullptr, nullptr, GIf, 768, 1024, Tc, t0);
    k_gemm<0><<<dim3(Mc / 128, 6), 256, 0, stream>>>(gi, 1024, 0, nullptr, 0, Wih_b, bih_b,
                                                     nullptr, nullptr, GIb, 768, 1024, Tc, t0);
    k_recur<<<128, 512, 0, stream>>>(GIf, GIb, Whh_f, Whh_b, bhh_f, bhh_b,
                                     out, hstate, Tc, t0, (c == 0) ? 1 : 0);
  }
}

// Round 5
// 2217.435 us; speedup vs baseline: 2.4563x; 1.5094x over previous
//
#include <hip/hip_runtime.h>

typedef unsigned short u16;
typedef __fp16 h2 __attribute__((ext_vector_type(2)));
typedef __attribute__((ext_vector_type(8))) short bf16x8;   // 8 bf16 = 4 VGPRs
typedef __attribute__((ext_vector_type(4))) float f32x4;

__device__ __forceinline__ float fast_exp(float x) { return __expf(x); }
__device__ __forceinline__ float fast_rcp(float x) { return __builtin_amdgcn_rcpf(x); }
__device__ __forceinline__ float fast_tanh(float x) {
  float e = fast_exp(2.0f * x);            // 1 - 2/(e^{2x}+1), saturates correctly
  return 1.0f - 2.0f * fast_rcp(e + 1.0f);
}
__device__ __forceinline__ float fast_sigmoid(float x) {
  return fast_rcp(1.0f + fast_exp(-x));
}
__device__ __forceinline__ u16 f2bf(float x) {  // round-to-nearest-even
  unsigned u = __float_as_uint(x);
  return (u16)((u + 0x7fffu + ((u >> 16) & 1u)) >> 16);
}

// ---------------------------------------------------------------------------
// fp32 -> bf16 bulk convert (n4 float4-groups)
__global__ __launch_bounds__(256)
void k_cvt(const float* __restrict__ src, u16* __restrict__ dst, int n4)
{
  int i = blockIdx.x * 256 + threadIdx.x;
  if (i < n4) {
    float4 x = ((const float4*)src)[i];
    ushort4 o;
    o.x = f2bf(x.x); o.y = f2bf(x.y); o.z = f2bf(x.z); o.w = f2bf(x.w);
    ((ushort4*)dst)[i] = o;
  }
}

// ---------------------------------------------------------------------------
// fp32 vector GEMM (kept for cm/cwm -- they feed softmax via tanh, where bf16
// input rounding would be amplified ~sqrt(512)*softmax; gate paths use k_mgemm).
// C = A @ W^T + bias. map1==1: A row m -> v row (m/Tc)*320 + t0 + m%Tc.
__global__ __launch_bounds__(256)
void k_gemm(const float* __restrict__ A1, int K1, int map1,
            const float* __restrict__ W,
            const float* __restrict__ bias,
            float* __restrict__ C, int N, int K, int Tc, int t0)
{
  __shared__ float As[16][128];
  __shared__ float Bs[16][128];
  const int tid = threadIdx.x;
  const int m0 = blockIdx.x * 128;
  const int n0 = blockIdx.y * 128;
  const int q = tid & 3;

  const float* pA1[2];
  const float* pW[2];
#pragma unroll
  for (int r = 0; r < 2; ++r) {
    int row = m0 + r * 64 + (tid >> 2);
    int ar1 = map1 ? ((row / Tc) * 320 + t0 + row % Tc) : row;
    pA1[r] = A1 + (size_t)ar1 * K1;
    pW[r] = W + (size_t)(n0 + r * 64 + (tid >> 2)) * K;
  }

  float acc[8][8];
#pragma unroll
  for (int i = 0; i < 8; ++i)
#pragma unroll
    for (int j = 0; j < 8; ++j) acc[i][j] = 0.f;
  const int tm = (tid & 15) * 8;
  const int tn = (tid >> 4) * 8;

  for (int k0 = 0; k0 < K; k0 += 16) {
#pragma unroll
    for (int r = 0; r < 2; ++r) {
      int row = r * 64 + (tid >> 2);
      int kk = k0 + q * 4;
      float4 x = *(const float4*)(pA1[r] + kk);
      As[q * 4 + 0][row] = x.x;
      As[q * 4 + 1][row] = x.y;
      As[q * 4 + 2][row] = x.z;
      As[q * 4 + 3][row] = x.w;
      float4 y = *(const float4*)(pW[r] + kk);
      Bs[q * 4 + 0][row] = y.x;
      Bs[q * 4 + 1][row] = y.y;
      Bs[q * 4 + 2][row] = y.z;
      Bs[q * 4 + 3][row] = y.w;
    }
    __syncthreads();
#pragma unroll
    for (int k = 0; k < 16; ++k) {
      float a[8], b[8];
      *(float4*)&a[0] = *(const float4*)&As[k][tm];
      *(float4*)&a[4] = *(const float4*)&As[k][tm + 4];
      *(float4*)&b[0] = *(const float4*)&Bs[k][tn];
      *(float4*)&b[4] = *(const float4*)&Bs[k][tn + 4];
#pragma unroll
      for (int i = 0; i < 8; ++i)
#pragma unroll
        for (int j = 0; j < 8; ++j) acc[i][j] += a[i] * b[j];
    }
    __syncthreads();
  }
#pragma unroll
  for (int i = 0; i < 8; ++i) {
    int m = m0 + tm + i;
    float* Crow = C + (size_t)m * N + n0 + tn;
#pragma unroll
    for (int j = 0; j < 8; ++j) Crow[j] = acc[i][j] + bias[n0 + tn + j];
  }
}

// ---------------------------------------------------------------------------
// bf16 MFMA GEMM: C = epilogue(A @ W16^T + bias). A is bf16 (M,K) k-contig,
// split [A1 (.,K1) | A2] (A2 identity-mapped); map1 chunk-maps A1/E1 rows into
// v. W16 bf16 (N,K). 128x128 block, BK=32, 4 waves (2x2 of 64x64), each wave
// 4x4 of 16x16x32 MFMA. Frag layouts per cdna4 guide (m89/m91-verified):
// A/B: [row=lane&15][k=(lane>>4)*8+j]; C/D: col=lane&15, row=(lane>>4)*4+reg.
// MODE 0: fp32 C = acc + bias.  MODE 1: bf16 C = pg*sigmoid(acc+bias),
// pg = [E1(v,fp32,row-mapped) | E2(cell,fp32)].
template<int MODE>
__global__ __launch_bounds__(256)
void k_mgemm(const u16* __restrict__ A1, int K1, int map1,
             const u16* __restrict__ A2,
             const u16* __restrict__ W16, const float* __restrict__ bias,
             const float* __restrict__ E1, const float* __restrict__ E2,
             void* __restrict__ Cout, int N, int K, int Tc, int t0)
{
  __shared__ alignas(16) u16 As[128][40];   // +8 pad: 80B row stride
  __shared__ alignas(16) u16 Bs[128][40];
  const int tid = threadIdx.x;
  const int m0 = blockIdx.x * 128;
  const int n0 = blockIdx.y * 128;
  const int wave = tid >> 6, lane = tid & 63;
  const int wm = (wave & 1) * 64, wn = (wave >> 1) * 64;
  const int K2 = K - K1;

  const u16* pA1r[2];
  const u16* pA2r[2];
  const u16* pWr[2];
#pragma unroll
  for (int r = 0; r < 2; ++r) {
    int row = r * 64 + (tid >> 2);
    int gm = m0 + row;
    int ar1 = map1 ? ((gm / Tc) * 320 + t0 + gm % Tc) : gm;
    pA1r[r] = A1 + (size_t)ar1 * K1;
    pA2r[r] = A2 ? (A2 + (size_t)gm * K2) : pA1r[r];   // A2 never mapped
    pWr[r] = W16 + (size_t)(n0 + row) * K;
  }

  f32x4 acc[4][4];
#pragma unroll
  for (int a = 0; a < 4; ++a)
#pragma unroll
    for (int b = 0; b < 4; ++b) acc[a][b] = (f32x4){0.f, 0.f, 0.f, 0.f};

  const int lrow = lane & 15, lq = lane >> 4;

  for (int k0 = 0; k0 < K; k0 += 32) {
#pragma unroll
    for (int r = 0; r < 2; ++r) {
      int row = r * 64 + (tid >> 2);
      int kk = k0 + (tid & 3) * 8;
      const u16* s = (kk < K1) ? (pA1r[r] + kk) : (pA2r[r] + (kk - K1));
      *(int4*)&As[row][(tid & 3) * 8] = *(const int4*)s;
      *(int4*)&Bs[row][(tid & 3) * 8] = *(const int4*)(pWr[r] + kk);
    }
    __syncthreads();
    bf16x8 av[4], bv[4];
#pragma unroll
    for (int f = 0; f < 4; ++f) {
      av[f] = *(const bf16x8*)&As[wm + f * 16 + lrow][lq * 8];
      bv[f] = *(const bf16x8*)&Bs[wn + f * 16 + lrow][lq * 8];
    }
#pragma unroll
    for (int mf = 0; mf < 4; ++mf)
#pragma unroll
      for (int nf = 0; nf < 4; ++nf)
        acc[mf][nf] = __builtin_amdgcn_mfma_f32_16x16x32_bf16(
            av[mf], bv[nf], acc[mf][nf], 0, 0, 0);
    __syncthreads();
  }

  // epilogue: lane holds C[m=rg*4+r][n=c] per fragment
  const int c = lane & 15, rg = lane >> 4;
#pragma unroll
  for (int mf = 0; mf < 4; ++mf) {
#pragma unroll
    for (int r = 0; r < 4; ++r) {
      int m = m0 + wm + mf * 16 + rg * 4 + r;
      int vrow = map1 ? ((m / Tc) * 320 + t0 + m % Tc) : m;
#pragma unroll
      for (int nf = 0; nf < 4; ++nf) {
        int n = n0 + wn + nf * 16 + c;
        float x = acc[mf][nf][r] + bias[n];
        if (MODE == 1) {
          float pg = (n < 512) ? E1[(size_t)vrow * 512 + n]
                               : E2[(size_t)m * 512 + (n - 512)];
          ((u16*)Cout)[(size_t)m * N + n] = f2bf(pg * fast_sigmoid(x));
        } else {
          ((float*)Cout)[(size_t)m * N + n] = x;
        }
      }
    }
  }
}

// ---------------------------------------------------------------------------
// sc[b,tl,s] = sum_d v[b,t0+tl,d] * tanh(cwm[b,tl,d] + cm[b,s,d])
__global__ __launch_bounds__(256)
void k_scores(const float* __restrict__ v, const float* __restrict__ cwm,
              const float* __restrict__ cm, float* __restrict__ sc,
              int Tc, int t0)
{
  __shared__ float vs[32][68], fs[32][68], cs[32][68];
  const int b = blockIdx.x;
  const int tl0 = blockIdx.y * 32;
  const int s0 = blockIdx.z * 32;
  const int tid = threadIdx.x;
  const int tx = tid & 15, ty = tid >> 4;
  const float* srcV = v   + ((size_t)b * 320 + t0 + tl0) * 512;
  const float* srcF = cwm + ((size_t)b * Tc + tl0) * 512;
  const float* srcC = cm  + ((size_t)b * 320 + s0) * 512;
  float a00 = 0, a01 = 0, a10 = 0, a11 = 0;
  for (int d0 = 0; d0 < 512; d0 += 64) {
#pragma unroll
    for (int r = 0; r < 2; ++r) {
      int f = r * 256 + tid;       // 512 f4 per array: 32 rows x 16 f4
      int row = f >> 4, qq = f & 15;
      *(float4*)&vs[row][qq * 4] = *(const float4*)(srcV + (size_t)row * 512 + d0 + qq * 4);
      *(float4*)&fs[row][qq * 4] = *(const float4*)(srcF + (size_t)row * 512 + d0 + qq * 4);
      *(float4*)&cs[row][qq * 4] = *(const float4*)(srcC + (size_t)row * 512 + d0 + qq * 4);
    }
    __syncthreads();
#pragma unroll 4
    for (int d = 0; d < 64; ++d) {
      float c0 = cs[tx][d], c1 = cs[tx + 16][d];
      float v0 = vs[ty][d], v1 = vs[ty + 16][d];
      float w0 = fs[ty][d], w1 = fs[ty + 16][d];
      a00 += v0 * fast_tanh(w0 + c0);
      a01 += v0 * fast_tanh(w0 + c1);
      a10 += v1 * fast_tanh(w1 + c0);
      a11 += v1 * fast_tanh(w1 + c1);
    }
    __syncthreads();
  }
  float* o = sc + (size_t)b * Tc * 320;
  o[(size_t)(tl0 + ty) * 320 + s0 + tx]           = a00;
  o[(size_t)(tl0 + ty) * 320 + s0 + tx + 16]      = a01;
  o[(size_t)(tl0 + ty + 16) * 320 + s0 + tx]      = a10;
  o[(size_t)(tl0 + ty + 16) * 320 + s0 + tx + 16] = a11;
}

// ---------------------------------------------------------------------------
// In-place softmax over last dim (320). One wave per row; grid covers rows/4.
__global__ __launch_bounds__(256)
void k_softmax(float* __restrict__ sc)
{
  int wave = threadIdx.x >> 6;
  int lane = threadIdx.x & 63;
  int row = blockIdx.x * 4 + wave;
  float* p = sc + (size_t)row * 320;
  float x[5];
  float mx = -1e30f;
#pragma unroll
  for (int j = 0; j < 5; ++j) { x[j] = p[lane + 64 * j]; mx = fmaxf(mx, x[j]); }
#pragma unroll
  for (int off = 32; off > 0; off >>= 1) mx = fmaxf(mx, __shfl_xor(mx, off));
  float s = 0.f;
#pragma unroll
  for (int j = 0; j < 5; ++j) { x[j] = fast_exp(x[j] - mx); s += x[j]; }
#pragma unroll
  for (int off = 32; off > 0; off >>= 1) s += __shfl_xor(s, off);
  float rinv = fast_rcp(s);
#pragma unroll
  for (int j = 0; j < 5; ++j) p[lane + 64 * j] = x[j] * rinv;
}

// ---------------------------------------------------------------------------
// cell[b,tl,d] = sum_s attn[b,tl,s] * v[b,s,d]; also emits cell16 (bf16) for
// the downstream bf16-MFMA Wg gemm. 32x64 tile (Tc multiple of 32).
__global__ __launch_bounds__(256)
void k_cell(const float* __restrict__ attn, const float* __restrict__ v,
            float* __restrict__ cell, u16* __restrict__ cell16, int Tc)
{
  __shared__ float As[16][32], Bs[16][64];
  const int b = blockIdx.x;
  const int m0 = blockIdx.y * 32;
  const int n0 = blockIdx.z * 64;
  const int tid = threadIdx.x;
  const float* A = attn + (size_t)b * Tc * 320;
  const float* B = v + (size_t)b * 320 * 512;
  float acc[2][4];
#pragma unroll
  for (int i = 0; i < 2; ++i)
#pragma unroll
    for (int j = 0; j < 4; ++j) acc[i][j] = 0.f;
  const int tm = (tid & 15) * 2, tn = (tid >> 4) * 4;
  for (int k0 = 0; k0 < 320; k0 += 16) {
    if (tid < 128) {
      int row = tid >> 2, q = tid & 3;          // A: 32 rows x 4 f4
      float4 x = *(const float4*)(A + (size_t)(m0 + row) * 320 + k0 + q * 4);
      As[q * 4 + 0][row] = x.x;
      As[q * 4 + 1][row] = x.y;
      As[q * 4 + 2][row] = x.z;
      As[q * 4 + 3][row] = x.w;
    }
    {
      int krow = tid >> 4, qq = tid & 15;       // B: 16 k-rows x 16 f4
      *(float4*)&Bs[krow][qq * 4] =
          *(const float4*)(B + (size_t)(k0 + krow) * 512 + n0 + qq * 4);
    }
    __syncthreads();
#pragma unroll
    for (int k = 0; k < 16; ++k) {
      float a0 = As[k][tm], a1 = As[k][tm + 1];
      float bb[4];
      *(float4*)&bb[0] = *(const float4*)&Bs[k][tn];
#pragma unroll
      for (int j = 0; j < 4; ++j) { acc[0][j] += a0 * bb[j]; acc[1][j] += a1 * bb[j]; }
    }
    __syncthreads();
  }
#pragma unroll
  for (int i = 0; i < 2; ++i) {
    size_t off = ((size_t)b * Tc + m0 + tm + i) * 512 + n0 + tn;
    float4 o = make_float4(acc[i][0], acc[i][1], acc[i][2], acc[i][3]);
    *(float4*)(cell + off) = o;
    ushort4 o16;
    o16.x = f2bf(o.x); o16.y = f2bf(o.y); o16.z = f2bf(o.z); o16.w = f2bf(o.w);
    *(ushort4*)(cell16 + off) = o16;
  }
}

// ---------------------------------------------------------------------------
// Sequential GRU; one block per (b,dir), 512 threads; Whh register-resident f16.
__global__ __launch_bounds__(512)
void k_recur(const float* __restrict__ GIf, const float* __restrict__ GIb,
             const float* __restrict__ Whh_f, const float* __restrict__ Whh_b,
             const float* __restrict__ bhh_f, const float* __restrict__ bhh_b,
             float* __restrict__ out, float* __restrict__ hstate,
             int Tc, int t0, int init)
{
  const int b = blockIdx.x >> 1;
  const int dir = blockIdx.x & 1;
  const int tid = threadIdx.x;
  const int i = tid & 255;
  const int half = __builtin_amdgcn_readfirstlane(tid >> 8);  // wave-uniform
  const int lane = tid & 63;

  __shared__ float part[3][256];          // half1 partial acc (r,z,n)
  __shared__ alignas(8) __fp16 hh16[256];

  const float* Wh  = dir ? Whh_b : Whh_f;
  const float* bhh = dir ? bhh_b : bhh_f;
  const float* GI  = (dir ? GIb : GIf) + (size_t)b * Tc * 768;

  // ---- load this thread's weight slice into registers (f16 pairs) ----
  h2 wr[64], wz[64], wn[64];
  {
    const float* Wr = Wh + (size_t)i * 256 + half * 128;
    const float* Wz = Wh + (size_t)(256 + i) * 256 + half * 128;
    const float* Wn = Wh + (size_t)(512 + i) * 256 + half * 128;
#pragma unroll
    for (int qd = 0; qd < 32; ++qd) {
      float4 x = *(const float4*)(Wr + 4 * qd);
      wr[2 * qd]     = __builtin_amdgcn_cvt_pkrtz(x.x, x.y);
      wr[2 * qd + 1] = __builtin_amdgcn_cvt_pkrtz(x.z, x.w);
      float4 y = *(const float4*)(Wz + 4 * qd);
      wz[2 * qd]     = __builtin_amdgcn_cvt_pkrtz(y.x, y.y);
      wz[2 * qd + 1] = __builtin_amdgcn_cvt_pkrtz(y.z, y.w);
      float4 zv = *(const float4*)(Wn + 4 * qd);
      wn[2 * qd]     = __builtin_amdgcn_cvt_pkrtz(zv.x, zv.y);
      wn[2 * qd + 1] = __builtin_amdgcn_cvt_pkrtz(zv.z, zv.w);
    }
  }

  float br = 0.f, bz = 0.f, bn = 0.f, hown = 0.f;
  if (half == 0) {
    br = bhh[i]; bz = bhh[256 + i]; bn = bhh[512 + i];
    hown = init ? 0.f : hstate[(size_t)blockIdx.x * 256 + i];
    hh16[i] = (__fp16)hown;
  }
  float* op = out + (size_t)t0 * 32768 + (size_t)b * 512 + dir * 256 + i;
  __syncthreads();

  // distributed h: lane L holds halves 4L..4L+3 as two packed pairs
  int2 hp = *(const int2*)((const char*)hh16 + 8 * lane);

  for (int t = 0; t < Tc; ++t) {
    const float* gi = GI + (size_t)t * 768;
    float gr = 0.f, gz = 0.f, gn = 0.f;
    if (half == 0) { gr = gi[i]; gz = gi[256 + i]; gn = gi[512 + i]; }

    float ar = 0.f, az = 0.f, an = 0.f;
    const int lbase = half * 32;
#pragma unroll
    for (int p = 0; p < 64; ++p) {
      int src = (p & 1) ? hp.y : hp.x;
      h2 hh = __builtin_bit_cast(h2, __builtin_amdgcn_readlane(src, lbase + (p >> 1)));
      ar = __builtin_amdgcn_fdot2(wr[p], hh, ar, false);
      az = __builtin_amdgcn_fdot2(wz[p], hh, az, false);
      an = __builtin_amdgcn_fdot2(wn[p], hh, an, false);
    }
    if (half == 1) {
      part[0][i] = ar; part[1][i] = az; part[2][i] = an;
    }
    __syncthreads();                       // A: partials visible
    if (half == 0) {
      float r  = fast_sigmoid(gr + ar + part[0][i] + br);
      float z  = fast_sigmoid(gz + az + part[1][i] + bz);
      float nn = fast_tanh(gn + r * (an + part[2][i] + bn));
      hown = (1.f - z) * nn + z * hown;
      op[(size_t)t * 32768] = hown;        // out[t0+t, b, dir*256+i]
      hh16[i] = (__fp16)hown;
    }
    __syncthreads();                       // B: new h visible
    hp = *(const int2*)((const char*)hh16 + 8 * lane);
  }
  if (half == 0) hstate[(size_t)blockIdx.x * 256 + i] = hown;
}

// ---------------------------------------------------------------------------
extern "C" void kernel_launch(void* const* d_in, const int* in_sizes, int n_in,
                              void* d_out, int out_size, void* d_ws, size_t ws_size,
                              hipStream_t stream)
{
  const float* v     = (const float*)d_in[0];
  const float* W1    = (const float*)d_in[1];
  const float* b1    = (const float*)d_in[2];
  const float* W2    = (const float*)d_in[3];
  const float* b2    = (const float*)d_in[4];
  const float* Wg    = (const float*)d_in[5];
  const float* bg    = (const float*)d_in[6];
  const float* Wih_f = (const float*)d_in[7];
  const float* Whh_f = (const float*)d_in[8];
  const float* bih_f = (const float*)d_in[9];
  const float* bhh_f = (const float*)d_in[10];
  const float* Wih_b = (const float*)d_in[11];
  const float* Whh_b = (const float*)d_in[12];
  const float* bih_b = (const float*)d_in[13];
  const float* bhh_b = (const float*)d_in[14];
  float* out = (float*)d_out;
  float* w = (float*)d_ws;

  // Largest chunk that fits: bytes = 4*(17072128 + 233472*Tc).
  // Tc=320 -> 367 MB, 160 -> 218 MB, 64 -> 128 MB, 32 -> 98 MB.
  int Tc = 32;
  {
    const int cand[4] = {320, 160, 64, 32};
    for (int ci = 0; ci < 4; ++ci) {
      size_t need = 4ull * (17072128ull + 233472ull * (size_t)cand[ci]);
      if (need <= ws_size) { Tc = cand[ci]; break; }
    }
  }
  const int nc = 320 / Tc;

  // Workspace layout (float units)
  float* cm     = w;                                   // 10485760
  float* hstate = w + 10485760;                        // 32768
  u16*  v16     = (u16*)(w + 10518528);                // 10485760 halfs
  u16*  Wg16    = (u16*)(w + 15761408);                // 1048576 halfs
  u16*  Wif16   = (u16*)(w + 16285696);                // 786432 halfs
  u16*  Wib16   = (u16*)(w + 16678912);                // 786432 halfs
  float* cwm    = w + 17072128;                        // 32768*Tc
  float* attn   = cwm  + (size_t)32768 * Tc;           // 20480*Tc
  float* cell   = attn + (size_t)20480 * Tc;           // 32768*Tc
  u16*  cell16  = (u16*)(cell + (size_t)32768 * Tc);   // 32768*Tc halfs
  u16*  gi16    = (u16*)(cell + (size_t)48152 * Tc + (size_t)1384 * Tc);  // placeholder (fixed below)
  // compute offsets explicitly in float units to avoid mistakes:
  {
    size_t base = 17072128;
    cwm    = w + base;                                  base += (size_t)32768 * Tc;
    attn   = w + base;                                  base += (size_t)20480 * Tc;
    cell   = w + base;                                  base += (size_t)32768 * Tc;
    cell16 = (u16*)(w + base);                          base += (size_t)16384 * Tc;
    gi16   = (u16*)(w + base);                          base += (size_t)32768 * Tc;
    hstate = hstate; // (unchanged)
    // GIf/GIb below
    float* GIf = w + base;                              base += (size_t)49152 * Tc;
    float* GIb = w + base;

    // ---- launches ----
    // weight/value bf16 conversions (every call; no static state allowed)
    k_cvt<<<(2621440 + 255) / 256, 256, 0, stream>>>(v, v16, 2621440);        // 20480*512/4
    k_cvt<<<(262144 + 255) / 256, 256, 0, stream>>>(Wg, Wg16, 262144);        // 1024*1024/4
    k_cvt<<<(196608 + 255) / 256, 256, 0, stream>>>(Wih_f, Wif16, 196608);    // 768*1024/4
    k_cvt<<<(196608 + 255) / 256, 256, 0, stream>>>(Wih_b, Wib16, 196608);

    // cm = v@W2^T + b2 (full rows, fp32 path: feeds tanh->softmax)
    k_gemm<<<dim3(160, 4), 256, 0, stream>>>(v, 512, 1, W2, b2, cm, 512, 512, 320, 0);

    for (int c = 0; c < nc; ++c) {
      const int t0 = c * Tc;
      const int Mc = 64 * Tc;
      // cwm = v_chunk@W1^T + b1 (fp32 path)
      k_gemm<<<dim3(Mc / 128, 4), 256, 0, stream>>>(v, 512, 1, W1, b1, cwm, 512, 512, Tc, t0);
      k_scores<<<dim3(64, Tc / 32, 10), 256, 0, stream>>>(v, cwm, cm, attn, Tc, t0);
      k_softmax<<<Mc / 4, 256, 0, stream>>>(attn);
      k_cell<<<dim3(64, Tc / 32, 8), 256, 0, stream>>>(attn, v, cell, cell16, Tc);
      // gi16 = bf16( pg * sigmoid(pg@Wg^T + bg) ), pg = [v|cell]  (bf16 MFMA)
      k_mgemm<1><<<dim3(Mc / 128, 8), 256, 0, stream>>>(v16, 512, 1, cell16, Wg16, bg,
                                                        v, cell, gi16, 1024, 1024, Tc, t0);
      // GI_f/b = gi@Wih^T + bih  (bf16 MFMA, fp32 out)
      k_mgemm<0><<<dim3(Mc / 128, 6), 256, 0, stream>>>(gi16, 1024, 0, nullptr, Wif16, bih_f,
                                                        nullptr, nullptr, GIf, 768, 1024, Tc, t0);
      k_mgemm<0><<<dim3(Mc / 128, 6), 256, 0, stream>>>(gi16, 1024, 0, nullptr, Wib16, bih_b,
                                                        nullptr, nullptr, GIb, 768, 1024, Tc, t0);
      k_recur<<<128, 512, 0, stream>>>(GIf, GIb, Whh_f, Whh_b, bhh_f, bhh_b,
                                       out, hstate, Tc, t0, (c == 0) ? 1 : 0);
    }
  }
}

// Round 6
// 1819.792 us; speedup vs baseline: 2.9930x; 1.2185x over previous
//
#include <hip/hip_runtime.h>

typedef unsigned short u16;
typedef __fp16 h2 __attribute__((ext_vector_type(2)));
typedef __attribute__((ext_vector_type(8))) short bf16x8;   // 8 bf16 = 4 VGPRs
typedef __attribute__((ext_vector_type(4))) float f32x4;

__device__ __forceinline__ float fast_exp(float x) { return __expf(x); }
__device__ __forceinline__ float fast_rcp(float x) { return __builtin_amdgcn_rcpf(x); }
__device__ __forceinline__ float fast_tanh(float x) {
  float e = fast_exp(2.0f * x);            // 1 - 2/(e^{2x}+1), saturates correctly
  return 1.0f - 2.0f * fast_rcp(e + 1.0f);
}
__device__ __forceinline__ float fast_sigmoid(float x) {
  return fast_rcp(1.0f + fast_exp(-x));
}
__device__ __forceinline__ u16 f2bf(float x) {  // round-to-nearest-even
  unsigned u = __float_as_uint(x);
  return (u16)((u + 0x7fffu + ((u >> 16) & 1u)) >> 16);
}

// ---------------------------------------------------------------------------
// fp32 -> bf16 bulk convert (n4 float4-groups)
__global__ __launch_bounds__(256)
void k_cvt(const float* __restrict__ src, u16* __restrict__ dst, int n4)
{
  int i = blockIdx.x * 256 + threadIdx.x;
  if (i < n4) {
    float4 x = ((const float4*)src)[i];
    ushort4 o;
    o.x = f2bf(x.x); o.y = f2bf(x.y); o.z = f2bf(x.z); o.w = f2bf(x.w);
    ((ushort4*)dst)[i] = o;
  }
}

// ---------------------------------------------------------------------------
// fp32 vector GEMM for cm/cwm (softmax-feeding paths stay fp32).
// C = A @ W^T + bias;  EXPOUT: store e^{2x} instead of x (k_scores consumes
// E=e^{2cwm}, F=e^{2cm} for the tanh(a+b)=1-2/(EF+1) identity).
// map1==1: A row m -> v row (m/Tc)*320 + t0 + m%Tc.
template<int EXPOUT>
__global__ __launch_bounds__(256)
void k_gemm(const float* __restrict__ A1, int K1, int map1,
            const float* __restrict__ W,
            const float* __restrict__ bias,
            float* __restrict__ C, int N, int K, int Tc, int t0)
{
  __shared__ float As[16][128];
  __shared__ float Bs[16][128];
  const int tid = threadIdx.x;
  const int m0 = blockIdx.x * 128;
  const int n0 = blockIdx.y * 128;
  const int q = tid & 3;

  const float* pA1[2];
  const float* pW[2];
#pragma unroll
  for (int r = 0; r < 2; ++r) {
    int row = m0 + r * 64 + (tid >> 2);
    int ar1 = map1 ? ((row / Tc) * 320 + t0 + row % Tc) : row;
    pA1[r] = A1 + (size_t)ar1 * K1;
    pW[r] = W + (size_t)(n0 + r * 64 + (tid >> 2)) * K;
  }

  float acc[8][8];
#pragma unroll
  for (int i = 0; i < 8; ++i)
#pragma unroll
    for (int j = 0; j < 8; ++j) acc[i][j] = 0.f;
  const int tm = (tid & 15) * 8;
  const int tn = (tid >> 4) * 8;

  for (int k0 = 0; k0 < K; k0 += 16) {
#pragma unroll
    for (int r = 0; r < 2; ++r) {
      int row = r * 64 + (tid >> 2);
      int kk = k0 + q * 4;
      float4 x = *(const float4*)(pA1[r] + kk);
      As[q * 4 + 0][row] = x.x;
      As[q * 4 + 1][row] = x.y;
      As[q * 4 + 2][row] = x.z;
      As[q * 4 + 3][row] = x.w;
      float4 y = *(const float4*)(pW[r] + kk);
      Bs[q * 4 + 0][row] = y.x;
      Bs[q * 4 + 1][row] = y.y;
      Bs[q * 4 + 2][row] = y.z;
      Bs[q * 4 + 3][row] = y.w;
    }
    __syncthreads();
#pragma unroll
    for (int k = 0; k < 16; ++k) {
      float a[8], b[8];
      *(float4*)&a[0] = *(const float4*)&As[k][tm];
      *(float4*)&a[4] = *(const float4*)&As[k][tm + 4];
      *(float4*)&b[0] = *(const float4*)&Bs[k][tn];
      *(float4*)&b[4] = *(const float4*)&Bs[k][tn + 4];
#pragma unroll
      for (int i = 0; i < 8; ++i)
#pragma unroll
        for (int j = 0; j < 8; ++j) acc[i][j] += a[i] * b[j];
    }
    __syncthreads();
  }
#pragma unroll
  for (int i = 0; i < 8; ++i) {
    int m = m0 + tm + i;
    float* Crow = C + (size_t)m * N + n0 + tn;
#pragma unroll
    for (int j = 0; j < 8; ++j) {
      float x = acc[i][j] + bias[n0 + tn + j];
      Crow[j] = EXPOUT ? fast_exp(2.0f * x) : x;
    }
  }
}

// ---------------------------------------------------------------------------
// bf16 MFMA GEMM: C = epilogue(A @ W16^T + bias). A is bf16 (M,K) k-contig,
// split [A1 (.,K1) | A2] (A2 identity-mapped); map1 chunk-maps A1/E1 rows into
// v. W16 bf16 (N,K). 128x128 block, BK=32, 4 waves (2x2 of 64x64), each wave
// 4x4 of 16x16x32 MFMA. Frag layouts per cdna4 guide (m89/m91-verified):
// A/B: [row=lane&15][k=(lane>>4)*8+j]; C/D: col=lane&15, row=(lane>>4)*4+reg.
// MODE 0: fp32 C = acc + bias.  MODE 1: bf16 C = pg*sigmoid(acc+bias),
// pg = [E1(v,fp32,row-mapped) | E2(cell,fp32)].
template<int MODE>
__global__ __launch_bounds__(256)
void k_mgemm(const u16* __restrict__ A1, int K1, int map1,
             const u16* __restrict__ A2,
             const u16* __restrict__ W16, const float* __restrict__ bias,
             const float* __restrict__ E1, const float* __restrict__ E2,
             void* __restrict__ Cout, int N, int K, int Tc, int t0)
{
  __shared__ alignas(16) u16 As[128][40];   // +8 pad: 80B row stride
  __shared__ alignas(16) u16 Bs[128][40];
  const int tid = threadIdx.x;
  const int m0 = blockIdx.x * 128;
  const int n0 = blockIdx.y * 128;
  const int wave = tid >> 6, lane = tid & 63;
  const int wm = (wave & 1) * 64, wn = (wave >> 1) * 64;
  const int K2 = K - K1;

  const u16* pA1r[2];
  const u16* pA2r[2];
  const u16* pWr[2];
#pragma unroll
  for (int r = 0; r < 2; ++r) {
    int row = r * 64 + (tid >> 2);
    int gm = m0 + row;
    int ar1 = map1 ? ((gm / Tc) * 320 + t0 + gm % Tc) : gm;
    pA1r[r] = A1 + (size_t)ar1 * K1;
    pA2r[r] = A2 ? (A2 + (size_t)gm * K2) : pA1r[r];   // A2 never mapped
    pWr[r] = W16 + (size_t)(n0 + row) * K;
  }

  f32x4 acc[4][4];
#pragma unroll
  for (int a = 0; a < 4; ++a)
#pragma unroll
    for (int b = 0; b < 4; ++b) acc[a][b] = (f32x4){0.f, 0.f, 0.f, 0.f};

  const int lrow = lane & 15, lq = lane >> 4;

  for (int k0 = 0; k0 < K; k0 += 32) {
#pragma unroll
    for (int r = 0; r < 2; ++r) {
      int row = r * 64 + (tid >> 2);
      int kk = k0 + (tid & 3) * 8;
      const u16* s = (kk < K1) ? (pA1r[r] + kk) : (pA2r[r] + (kk - K1));
      *(int4*)&As[row][(tid & 3) * 8] = *(const int4*)s;
      *(int4*)&Bs[row][(tid & 3) * 8] = *(const int4*)(pWr[r] + kk);
    }
    __syncthreads();
    bf16x8 av[4], bv[4];
#pragma unroll
    for (int f = 0; f < 4; ++f) {
      av[f] = *(const bf16x8*)&As[wm + f * 16 + lrow][lq * 8];
      bv[f] = *(const bf16x8*)&Bs[wn + f * 16 + lrow][lq * 8];
    }
#pragma unroll
    for (int mf = 0; mf < 4; ++mf)
#pragma unroll
      for (int nf = 0; nf < 4; ++nf)
        acc[mf][nf] = __builtin_amdgcn_mfma_f32_16x16x32_bf16(
            av[mf], bv[nf], acc[mf][nf], 0, 0, 0);
    __syncthreads();
  }

  // epilogue: lane holds C[m=rg*4+r][n=c] per fragment
  const int c = lane & 15, rg = lane >> 4;
#pragma unroll
  for (int mf = 0; mf < 4; ++mf) {
#pragma unroll
    for (int r = 0; r < 4; ++r) {
      int m = m0 + wm + mf * 16 + rg * 4 + r;
      int vrow = map1 ? ((m / Tc) * 320 + t0 + m % Tc) : m;
#pragma unroll
      for (int nf = 0; nf < 4; ++nf) {
        int n = n0 + wn + nf * 16 + c;
        float x = acc[mf][nf][r] + bias[n];
        if (MODE == 1) {
          float pg = (n < 512) ? E1[(size_t)vrow * 512 + n]
                               : E2[(size_t)m * 512 + (n - 512)];
          ((u16*)Cout)[(size_t)m * N + n] = f2bf(pg * fast_sigmoid(x));
        } else {
          ((float*)Cout)[(size_t)m * N + n] = x;
        }
      }
    }
  }
}

// ---------------------------------------------------------------------------
// sc[b,tl,s] = sum_d v * tanh(cwm + cm) computed via the identity
// tanh(a+b) = 1 - 2/(E*F+1) with E=e^{2a}, F=e^{2b} PRECOMPUTED in the
// k_gemm<1> epilogues. Inner loop per element: fma + rcp + fma (1 transcendental
// vs 2 in the tanh form). score = vsum - 2*acc, vsum = sum_d v accumulated here.
__global__ __launch_bounds__(256)
void k_scores(const float* __restrict__ v, const float* __restrict__ Ecwm,
              const float* __restrict__ Fcm, float* __restrict__ sc,
              int Tc, int t0)
{
  __shared__ float vs[32][68], fs[32][68], cs[32][68];
  const int b = blockIdx.x;
  const int tl0 = blockIdx.y * 32;
  const int s0 = blockIdx.z * 32;
  const int tid = threadIdx.x;
  const int tx = tid & 15, ty = tid >> 4;
  const float* srcV = v    + ((size_t)b * 320 + t0 + tl0) * 512;
  const float* srcF = Ecwm + ((size_t)b * Tc + tl0) * 512;
  const float* srcC = Fcm  + ((size_t)b * 320 + s0) * 512;
  float a00 = 0, a01 = 0, a10 = 0, a11 = 0;
  float vs0 = 0, vs1 = 0;
  for (int d0 = 0; d0 < 512; d0 += 64) {
#pragma unroll
    for (int r = 0; r < 2; ++r) {
      int f = r * 256 + tid;       // 512 f4 per array: 32 rows x 16 f4
      int row = f >> 4, qq = f & 15;
      *(float4*)&vs[row][qq * 4] = *(const float4*)(srcV + (size_t)row * 512 + d0 + qq * 4);
      *(float4*)&fs[row][qq * 4] = *(const float4*)(srcF + (size_t)row * 512 + d0 + qq * 4);
      *(float4*)&cs[row][qq * 4] = *(const float4*)(srcC + (size_t)row * 512 + d0 + qq * 4);
    }
    __syncthreads();
#pragma unroll 4
    for (int d = 0; d < 64; ++d) {
      float c0 = cs[tx][d], c1 = cs[tx + 16][d];
      float e0 = fs[ty][d], e1 = fs[ty + 16][d];
      float v0 = vs[ty][d], v1 = vs[ty + 16][d];
      vs0 += v0; vs1 += v1;
      a00 = fmaf(v0, fast_rcp(fmaf(e0, c0, 1.0f)), a00);
      a01 = fmaf(v0, fast_rcp(fmaf(e0, c1, 1.0f)), a01);
      a10 = fmaf(v1, fast_rcp(fmaf(e1, c0, 1.0f)), a10);
      a11 = fmaf(v1, fast_rcp(fmaf(e1, c1, 1.0f)), a11);
    }
    __syncthreads();
  }
  float* o = sc + (size_t)b * Tc * 320;
  o[(size_t)(tl0 + ty) * 320 + s0 + tx]           = vs0 - 2.0f * a00;
  o[(size_t)(tl0 + ty) * 320 + s0 + tx + 16]      = vs0 - 2.0f * a01;
  o[(size_t)(tl0 + ty + 16) * 320 + s0 + tx]      = vs1 - 2.0f * a10;
  o[(size_t)(tl0 + ty + 16) * 320 + s0 + tx + 16] = vs1 - 2.0f * a11;
}

// ---------------------------------------------------------------------------
// In-place softmax over last dim (320). One wave per row; grid covers rows/4.
__global__ __launch_bounds__(256)
void k_softmax(float* __restrict__ sc)
{
  int wave = threadIdx.x >> 6;
  int lane = threadIdx.x & 63;
  int row = blockIdx.x * 4 + wave;
  float* p = sc + (size_t)row * 320;
  float x[5];
  float mx = -1e30f;
#pragma unroll
  for (int j = 0; j < 5; ++j) { x[j] = p[lane + 64 * j]; mx = fmaxf(mx, x[j]); }
#pragma unroll
  for (int off = 32; off > 0; off >>= 1) mx = fmaxf(mx, __shfl_xor(mx, off));
  float s = 0.f;
#pragma unroll
  for (int j = 0; j < 5; ++j) { x[j] = fast_exp(x[j] - mx); s += x[j]; }
#pragma unroll
  for (int off = 32; off > 0; off >>= 1) s += __shfl_xor(s, off);
  float rinv = fast_rcp(s);
#pragma unroll
  for (int j = 0; j < 5; ++j) p[lane + 64 * j] = x[j] * rinv;
}

// ---------------------------------------------------------------------------
// cell[b,tl,d] = sum_s attn[b,tl,s] * v[b,s,d]; also emits cell16 (bf16) for
// the downstream bf16-MFMA Wg gemm. 32x64 tile (Tc multiple of 32).
__global__ __launch_bounds__(256)
void k_cell(const float* __restrict__ attn, const float* __restrict__ v,
            float* __restrict__ cell, u16* __restrict__ cell16, int Tc)
{
  __shared__ float As[16][32], Bs[16][64];
  const int b = blockIdx.x;
  const int m0 = blockIdx.y * 32;
  const int n0 = blockIdx.z * 64;
  const int tid = threadIdx.x;
  const float* A = attn + (size_t)b * Tc * 320;
  const float* B = v + (size_t)b * 320 * 512;
  float acc[2][4];
#pragma unroll
  for (int i = 0; i < 2; ++i)
#pragma unroll
    for (int j = 0; j < 4; ++j) acc[i][j] = 0.f;
  const int tm = (tid & 15) * 2, tn = (tid >> 4) * 4;
  for (int k0 = 0; k0 < 320; k0 += 16) {
    if (tid < 128) {
      int row = tid >> 2, q = tid & 3;          // A: 32 rows x 4 f4
      float4 x = *(const float4*)(A + (size_t)(m0 + row) * 320 + k0 + q * 4);
      As[q * 4 + 0][row] = x.x;
      As[q * 4 + 1][row] = x.y;
      As[q * 4 + 2][row] = x.z;
      As[q * 4 + 3][row] = x.w;
    }
    {
      int krow = tid >> 4, qq = tid & 15;       // B: 16 k-rows x 16 f4
      *(float4*)&Bs[krow][qq * 4] =
          *(const float4*)(B + (size_t)(k0 + krow) * 512 + n0 + qq * 4);
    }
    __syncthreads();
#pragma unroll
    for (int k = 0; k < 16; ++k) {
      float a0 = As[k][tm], a1 = As[k][tm + 1];
      float bb[4];
      *(float4*)&bb[0] = *(const float4*)&Bs[k][tn];
#pragma unroll
      for (int j = 0; j < 4; ++j) { acc[0][j] += a0 * bb[j]; acc[1][j] += a1 * bb[j]; }
    }
    __syncthreads();
  }
#pragma unroll
  for (int i = 0; i < 2; ++i) {
    size_t off = ((size_t)b * Tc + m0 + tm + i) * 512 + n0 + tn;
    float4 o = make_float4(acc[i][0], acc[i][1], acc[i][2], acc[i][3]);
    *(float4*)(cell + off) = o;
    ushort4 o16;
    o16.x = f2bf(o.x); o16.y = f2bf(o.y); o16.z = f2bf(o.z); o16.w = f2bf(o.w);
    *(ushort4*)(cell16 + off) = o16;
  }
}

// ---------------------------------------------------------------------------
// Sequential GRU; one block per (b,dir), 512 threads; Whh register-resident f16.
__global__ __launch_bounds__(512)
void k_recur(const float* __restrict__ GIf, const float* __restrict__ GIb,
             const float* __restrict__ Whh_f, const float* __restrict__ Whh_b,
             const float* __restrict__ bhh_f, const float* __restrict__ bhh_b,
             float* __restrict__ out, float* __restrict__ hstate,
             int Tc, int t0, int init)
{
  const int b = blockIdx.x >> 1;
  const int dir = blockIdx.x & 1;
  const int tid = threadIdx.x;
  const int i = tid & 255;
  const int half = __builtin_amdgcn_readfirstlane(tid >> 8);  // wave-uniform
  const int lane = tid & 63;

  __shared__ float part[3][256];          // half1 partial acc (r,z,n)
  __shared__ alignas(8) __fp16 hh16[256];

  const float* Wh  = dir ? Whh_b : Whh_f;
  const float* bhh = dir ? bhh_b : bhh_f;
  const float* GI  = (dir ? GIb : GIf) + (size_t)b * Tc * 768;

  // ---- load this thread's weight slice into registers (f16 pairs) ----
  h2 wr[64], wz[64], wn[64];
  {
    const float* Wr = Wh + (size_t)i * 256 + half * 128;
    const float* Wz = Wh + (size_t)(256 + i) * 256 + half * 128;
    const float* Wn = Wh + (size_t)(512 + i) * 256 + half * 128;
#pragma unroll
    for (int qd = 0; qd < 32; ++qd) {
      float4 x = *(const float4*)(Wr + 4 * qd);
      wr[2 * qd]     = __builtin_amdgcn_cvt_pkrtz(x.x, x.y);
      wr[2 * qd + 1] = __builtin_amdgcn_cvt_pkrtz(x.z, x.w);
      float4 y = *(const float4*)(Wz + 4 * qd);
      wz[2 * qd]     = __builtin_amdgcn_cvt_pkrtz(y.x, y.y);
      wz[2 * qd + 1] = __builtin_amdgcn_cvt_pkrtz(y.z, y.w);
      float4 zv = *(const float4*)(Wn + 4 * qd);
      wn[2 * qd]     = __builtin_amdgcn_cvt_pkrtz(zv.x, zv.y);
      wn[2 * qd + 1] = __builtin_amdgcn_cvt_pkrtz(zv.z, zv.w);
    }
  }

  float br = 0.f, bz = 0.f, bn = 0.f, hown = 0.f;
  if (half == 0) {
    br = bhh[i]; bz = bhh[256 + i]; bn = bhh[512 + i];
    hown = init ? 0.f : hstate[(size_t)blockIdx.x * 256 + i];
    hh16[i] = (__fp16)hown;
  }
  float* op = out + (size_t)t0 * 32768 + (size_t)b * 512 + dir * 256 + i;
  __syncthreads();

  // distributed h: lane L holds halves 4L..4L+3 as two packed pairs
  int2 hp = *(const int2*)((const char*)hh16 + 8 * lane);

  for (int t = 0; t < Tc; ++t) {
    const float* gi = GI + (size_t)t * 768;
    float gr = 0.f, gz = 0.f, gn = 0.f;
    if (half == 0) { gr = gi[i]; gz = gi[256 + i]; gn = gi[512 + i]; }

    float ar = 0.f, az = 0.f, an = 0.f;
    const int lbase = half * 32;
#pragma unroll
    for (int p = 0; p < 64; ++p) {
      int src = (p & 1) ? hp.y : hp.x;
      h2 hh = __builtin_bit_cast(h2, __builtin_amdgcn_readlane(src, lbase + (p >> 1)));
      ar = __builtin_amdgcn_fdot2(wr[p], hh, ar, false);
      az = __builtin_amdgcn_fdot2(wz[p], hh, az, false);
      an = __builtin_amdgcn_fdot2(wn[p], hh, an, false);
    }
    if (half == 1) {
      part[0][i] = ar; part[1][i] = az; part[2][i] = an;
    }
    __syncthreads();                       // A: partials visible
    if (half == 0) {
      float r  = fast_sigmoid(gr + ar + part[0][i] + br);
      float z  = fast_sigmoid(gz + az + part[1][i] + bz);
      float nn = fast_tanh(gn + r * (an + part[2][i] + bn));
      hown = (1.f - z) * nn + z * hown;
      op[(size_t)t * 32768] = hown;        // out[t0+t, b, dir*256+i]
      hh16[i] = (__fp16)hown;
    }
    __syncthreads();                       // B: new h visible
    hp = *(const int2*)((const char*)hh16 + 8 * lane);
  }
  if (half == 0) hstate[(size_t)blockIdx.x * 256 + i] = hown;
}

// ---------------------------------------------------------------------------
extern "C" void kernel_launch(void* const* d_in, const int* in_sizes, int n_in,
                              void* d_out, int out_size, void* d_ws, size_t ws_size,
                              hipStream_t stream)
{
  const float* v     = (const float*)d_in[0];
  const float* W1    = (const float*)d_in[1];
  const float* b1    = (const float*)d_in[2];
  const float* W2    = (const float*)d_in[3];
  const float* b2    = (const float*)d_in[4];
  const float* Wg    = (const float*)d_in[5];
  const float* bg    = (const float*)d_in[6];
  const float* Wih_f = (const float*)d_in[7];
  const float* Whh_f = (const float*)d_in[8];
  const float* bih_f = (const float*)d_in[9];
  const float* bhh_f = (const float*)d_in[10];
  const float* Wih_b = (const float*)d_in[11];
  const float* Whh_b = (const float*)d_in[12];
  const float* bih_b = (const float*)d_in[13];
  const float* bhh_b = (const float*)d_in[14];
  float* out = (float*)d_out;
  float* w = (float*)d_ws;

  // Largest chunk that fits: bytes = 4*(17072128 + 233472*Tc).
  // Tc=320 -> 367 MB, 160 -> 218 MB, 64 -> 128 MB, 32 -> 98 MB.
  int Tc = 32;
  {
    const int cand[4] = {320, 160, 64, 32};
    for (int ci = 0; ci < 4; ++ci) {
      size_t need = 4ull * (17072128ull + 233472ull * (size_t)cand[ci]);
      if (need <= ws_size) { Tc = cand[ci]; break; }
    }
  }
  const int nc = 320 / Tc;

  // Workspace layout (float units)
  float* cm     = w;                                   // 10485760 (stores e^{2cm})
  float* hstate = w + 10485760;                        // 32768
  u16*  v16     = (u16*)(w + 10518528);                // 10485760 halfs
  u16*  Wg16    = (u16*)(w + 15761408);                // 1048576 halfs
  u16*  Wif16   = (u16*)(w + 16285696);                // 786432 halfs
  u16*  Wib16   = (u16*)(w + 16678912);                // 786432 halfs
  {
    size_t base = 17072128;
    float* cwm;  float* attn;  float* cell;  u16* cell16;  u16* gi16;
    cwm    = w + base;                                  base += (size_t)32768 * Tc;
    attn   = w + base;                                  base += (size_t)20480 * Tc;
    cell   = w + base;                                  base += (size_t)32768 * Tc;
    cell16 = (u16*)(w + base);                          base += (size_t)16384 * Tc;
    gi16   = (u16*)(w + base);                          base += (size_t)32768 * Tc;
    float* GIf = w + base;                              base += (size_t)49152 * Tc;
    float* GIb = w + base;

    // ---- launches ----
    // weight/value bf16 conversions (every call; no static state allowed)
    k_cvt<<<(2621440 + 255) / 256, 256, 0, stream>>>(v, v16, 2621440);        // 20480*512/4
    k_cvt<<<(262144 + 255) / 256, 256, 0, stream>>>(Wg, Wg16, 262144);        // 1024*1024/4
    k_cvt<<<(196608 + 255) / 256, 256, 0, stream>>>(Wih_f, Wif16, 196608);    // 768*1024/4
    k_cvt<<<(196608 + 255) / 256, 256, 0, stream>>>(Wih_b, Wib16, 196608);

    // cm = e^{2(v@W2^T + b2)} (full rows, fp32 path: feeds scores identity)
    k_gemm<1><<<dim3(160, 4), 256, 0, stream>>>(v, 512, 1, W2, b2, cm, 512, 512, 320, 0);

    for (int c = 0; c < nc; ++c) {
      const int t0 = c * Tc;
      const int Mc = 64 * Tc;
      // cwm = e^{2(v_chunk@W1^T + b1)} (fp32 path)
      k_gemm<1><<<dim3(Mc / 128, 4), 256, 0, stream>>>(v, 512, 1, W1, b1, cwm, 512, 512, Tc, t0);
      k_scores<<<dim3(64, Tc / 32, 10), 256, 0, stream>>>(v, cwm, cm, attn, Tc, t0);
      k_softmax<<<Mc / 4, 256, 0, stream>>>(attn);
      k_cell<<<dim3(64, Tc / 32, 8), 256, 0, stream>>>(attn, v, cell, cell16, Tc);
      // gi16 = bf16( pg * sigmoid(pg@Wg^T + bg) ), pg = [v|cell]  (bf16 MFMA)
      k_mgemm<1><<<dim3(Mc / 128, 8), 256, 0, stream>>>(v16, 512, 1, cell16, Wg16, bg,
                                                        v, cell, gi16, 1024, 1024, Tc, t0);
      // GI_f/b = gi@Wih^T + bih  (bf16 MFMA, fp32 out)
      k_mgemm<0><<<dim3(Mc / 128, 6), 256, 0, stream>>>(gi16, 1024, 0, nullptr, Wif16, bih_f,
                                                        nullptr, nullptr, GIf, 768, 1024, Tc, t0);
      k_mgemm<0><<<dim3(Mc / 128, 6), 256, 0, stream>>>(gi16, 1024, 0, nullptr, Wib16, bih_b,
                                                        nullptr, nullptr, GIb, 768, 1024, Tc, t0);
      k_recur<<<128, 512, 0, stream>>>(GIf, GIb, Whh_f, Whh_b, bhh_f, bhh_b,
                                       out, hstate, Tc, t0, (c == 0) ? 1 : 0);
    }
  }
}

// Round 7
// 1563.657 us; speedup vs baseline: 3.4833x; 1.1638x over previous
//
#include <hip/hip_runtime.h>

typedef unsigned short u16;
typedef __fp16 h2 __attribute__((ext_vector_type(2)));
typedef __attribute__((ext_vector_type(8))) short bf16x8;   // 8 bf16 = 4 VGPRs
typedef __attribute__((ext_vector_type(4))) float f32x4;

__device__ __forceinline__ float fast_exp(float x) { return __expf(x); }
__device__ __forceinline__ float fast_rcp(float x) { return __builtin_amdgcn_rcpf(x); }
__device__ __forceinline__ float fast_tanh(float x) {
  float e = fast_exp(2.0f * x);            // 1 - 2/(e^{2x}+1), saturates correctly
  return 1.0f - 2.0f * fast_rcp(e + 1.0f);
}
__device__ __forceinline__ float fast_sigmoid(float x) {
  return fast_rcp(1.0f + fast_exp(-x));
}
__device__ __forceinline__ u16 f2bf(float x) {  // round-to-nearest-even
  unsigned u = __float_as_uint(x);
  return (u16)((u + 0x7fffu + ((u >> 16) & 1u)) >> 16);
}
__device__ __forceinline__ float bf2f(u16 u) {
  return __uint_as_float(((unsigned)u) << 16);
}

// ---------------------------------------------------------------------------
// fp32 -> bf16 bulk convert (n4 float4-groups)
__global__ __launch_bounds__(256)
void k_cvt(const float* __restrict__ src, u16* __restrict__ dst, int n4)
{
  int i = blockIdx.x * 256 + threadIdx.x;
  if (i < n4) {
    float4 x = ((const float4*)src)[i];
    ushort4 o;
    o.x = f2bf(x.x); o.y = f2bf(x.y); o.z = f2bf(x.z); o.w = f2bf(x.w);
    ((ushort4*)dst)[i] = o;
  }
}

// ---------------------------------------------------------------------------
// fp32 -> (hi, lo) bf16 split: x ~= hi + lo, |err| ~ 2^-17 |x|.
__global__ __launch_bounds__(256)
void k_split(const float* __restrict__ src, u16* __restrict__ hi,
             u16* __restrict__ lo, int n4)
{
  int i = blockIdx.x * 256 + threadIdx.x;
  if (i < n4) {
    float4 x = ((const float4*)src)[i];
    ushort4 h, l;
    h.x = f2bf(x.x); l.x = f2bf(x.x - bf2f(h.x));
    h.y = f2bf(x.y); l.y = f2bf(x.y - bf2f(h.y));
    h.z = f2bf(x.z); l.z = f2bf(x.z - bf2f(h.z));
    h.w = f2bf(x.w); l.w = f2bf(x.w - bf2f(h.w));
    ((ushort4*)hi)[i] = h;
    ((ushort4*)lo)[i] = l;
  }
}

// ---------------------------------------------------------------------------
// Split-bf16 "fp32-accurate" MFMA GEMM for cm/cwm:
// C = e^{2(A@W^T + bias)} (EXPOUT=1) with A,W given as (hi,lo) bf16 pairs and
// A@W ~= Ahi·Whi + Ahi·Wlo + Alo·Whi (3 MFMAs / fragment; lo·lo ~2^-18 dropped).
// A rows always map into v: row m -> (m/Tc)*320 + t0 + m%Tc.
// 128x128 block, BK=32, 4 waves (2x2 of 64x64), 4x4 of 16x16x32 MFMA each.
template<int EXPOUT>
__global__ __launch_bounds__(256)
void k_sgemm(const u16* __restrict__ Ahi, const u16* __restrict__ Alo,
             const u16* __restrict__ Whi, const u16* __restrict__ Wlo,
             const float* __restrict__ bias,
             float* __restrict__ C, int N, int K, int Tc, int t0)
{
  __shared__ alignas(16) u16 Ah[128][40];   // +8 pad: 80B row stride
  __shared__ alignas(16) u16 Al[128][40];
  __shared__ alignas(16) u16 Bh[128][40];
  __shared__ alignas(16) u16 Bl[128][40];
  const int tid = threadIdx.x;
  const int m0 = blockIdx.x * 128;
  const int n0 = blockIdx.y * 128;
  const int wave = tid >> 6, lane = tid & 63;
  const int wm = (wave & 1) * 64, wn = (wave >> 1) * 64;

  const u16 *pAh[2], *pAl[2], *pBh[2], *pBl[2];
#pragma unroll
  for (int r = 0; r < 2; ++r) {
    int row = r * 64 + (tid >> 2);
    int gm = m0 + row;
    int ar = (gm / Tc) * 320 + t0 + gm % Tc;
    pAh[r] = Ahi + (size_t)ar * K;
    pAl[r] = Alo + (size_t)ar * K;
    int gn = n0 + row;
    pBh[r] = Whi + (size_t)gn * K;
    pBl[r] = Wlo + (size_t)gn * K;
  }

  f32x4 acc[4][4];
#pragma unroll
  for (int a = 0; a < 4; ++a)
#pragma unroll
    for (int b = 0; b < 4; ++b) acc[a][b] = (f32x4){0.f, 0.f, 0.f, 0.f};

  const int lrow = lane & 15, lq = lane >> 4;

  for (int k0 = 0; k0 < K; k0 += 32) {
#pragma unroll
    for (int r = 0; r < 2; ++r) {
      int row = r * 64 + (tid >> 2);
      int kk = k0 + (tid & 3) * 8;
      *(int4*)&Ah[row][(tid & 3) * 8] = *(const int4*)(pAh[r] + kk);
      *(int4*)&Al[row][(tid & 3) * 8] = *(const int4*)(pAl[r] + kk);
      *(int4*)&Bh[row][(tid & 3) * 8] = *(const int4*)(pBh[r] + kk);
      *(int4*)&Bl[row][(tid & 3) * 8] = *(const int4*)(pBl[r] + kk);
    }
    __syncthreads();
    bf16x8 avh[4], avl[4], bvh[4], bvl[4];
#pragma unroll
    for (int f = 0; f < 4; ++f) {
      avh[f] = *(const bf16x8*)&Ah[wm + f * 16 + lrow][lq * 8];
      avl[f] = *(const bf16x8*)&Al[wm + f * 16 + lrow][lq * 8];
      bvh[f] = *(const bf16x8*)&Bh[wn + f * 16 + lrow][lq * 8];
      bvl[f] = *(const bf16x8*)&Bl[wn + f * 16 + lrow][lq * 8];
    }
#pragma unroll
    for (int mf = 0; mf < 4; ++mf)
#pragma unroll
      for (int nf = 0; nf < 4; ++nf) {
        acc[mf][nf] = __builtin_amdgcn_mfma_f32_16x16x32_bf16(
            avh[mf], bvh[nf], acc[mf][nf], 0, 0, 0);
        acc[mf][nf] = __builtin_amdgcn_mfma_f32_16x16x32_bf16(
            avh[mf], bvl[nf], acc[mf][nf], 0, 0, 0);
        acc[mf][nf] = __builtin_amdgcn_mfma_f32_16x16x32_bf16(
            avl[mf], bvh[nf], acc[mf][nf], 0, 0, 0);
      }
    __syncthreads();
  }

  const int c = lane & 15, rg = lane >> 4;
#pragma unroll
  for (int mf = 0; mf < 4; ++mf) {
#pragma unroll
    for (int r = 0; r < 4; ++r) {
      int m = m0 + wm + mf * 16 + rg * 4 + r;
#pragma unroll
      for (int nf = 0; nf < 4; ++nf) {
        int n = n0 + wn + nf * 16 + c;
        float x = acc[mf][nf][r] + bias[n];
        C[(size_t)m * N + n] = EXPOUT ? fast_exp(2.0f * x) : x;
      }
    }
  }
}

// ---------------------------------------------------------------------------
// bf16 MFMA GEMM (gate paths): C = epilogue(A @ W16^T + bias). A bf16 (M,K)
// k-contig, split [A1 (.,K1) | A2]; map1 chunk-maps A1/E1 rows into v.
// MODE 0: fp32 C = acc + bias.  MODE 1: bf16 C = pg*sigmoid(acc+bias),
// pg = [E1(v,fp32,row-mapped) | E2(cell,fp32)].
template<int MODE>
__global__ __launch_bounds__(256)
void k_mgemm(const u16* __restrict__ A1, int K1, int map1,
             const u16* __restrict__ A2,
             const u16* __restrict__ W16, const float* __restrict__ bias,
             const float* __restrict__ E1, const float* __restrict__ E2,
             void* __restrict__ Cout, int N, int K, int Tc, int t0)
{
  __shared__ alignas(16) u16 As[128][40];   // +8 pad: 80B row stride
  __shared__ alignas(16) u16 Bs[128][40];
  const int tid = threadIdx.x;
  const int m0 = blockIdx.x * 128;
  const int n0 = blockIdx.y * 128;
  const int wave = tid >> 6, lane = tid & 63;
  const int wm = (wave & 1) * 64, wn = (wave >> 1) * 64;
  const int K2 = K - K1;

  const u16* pA1r[2];
  const u16* pA2r[2];
  const u16* pWr[2];
#pragma unroll
  for (int r = 0; r < 2; ++r) {
    int row = r * 64 + (tid >> 2);
    int gm = m0 + row;
    int ar1 = map1 ? ((gm / Tc) * 320 + t0 + gm % Tc) : gm;
    pA1r[r] = A1 + (size_t)ar1 * K1;
    pA2r[r] = A2 ? (A2 + (size_t)gm * K2) : pA1r[r];   // A2 never mapped
    pWr[r] = W16 + (size_t)(n0 + row) * K;
  }

  f32x4 acc[4][4];
#pragma unroll
  for (int a = 0; a < 4; ++a)
#pragma unroll
    for (int b = 0; b < 4; ++b) acc[a][b] = (f32x4){0.f, 0.f, 0.f, 0.f};

  const int lrow = lane & 15, lq = lane >> 4;

  for (int k0 = 0; k0 < K; k0 += 32) {
#pragma unroll
    for (int r = 0; r < 2; ++r) {
      int row = r * 64 + (tid >> 2);
      int kk = k0 + (tid & 3) * 8;
      const u16* s = (kk < K1) ? (pA1r[r] + kk) : (pA2r[r] + (kk - K1));
      *(int4*)&As[row][(tid & 3) * 8] = *(const int4*)s;
      *(int4*)&Bs[row][(tid & 3) * 8] = *(const int4*)(pWr[r] + kk);
    }
    __syncthreads();
    bf16x8 av[4], bv[4];
#pragma unroll
    for (int f = 0; f < 4; ++f) {
      av[f] = *(const bf16x8*)&As[wm + f * 16 + lrow][lq * 8];
      bv[f] = *(const bf16x8*)&Bs[wn + f * 16 + lrow][lq * 8];
    }
#pragma unroll
    for (int mf = 0; mf < 4; ++mf)
#pragma unroll
      for (int nf = 0; nf < 4; ++nf)
        acc[mf][nf] = __builtin_amdgcn_mfma_f32_16x16x32_bf16(
            av[mf], bv[nf], acc[mf][nf], 0, 0, 0);
    __syncthreads();
  }

  // epilogue: lane holds C[m=rg*4+r][n=c] per fragment
  const int c = lane & 15, rg = lane >> 4;
#pragma unroll
  for (int mf = 0; mf < 4; ++mf) {
#pragma unroll
    for (int r = 0; r < 4; ++r) {
      int m = m0 + wm + mf * 16 + rg * 4 + r;
      int vrow = map1 ? ((m / Tc) * 320 + t0 + m % Tc) : m;
#pragma unroll
      for (int nf = 0; nf < 4; ++nf) {
        int n = n0 + wn + nf * 16 + c;
        float x = acc[mf][nf][r] + bias[n];
        if (MODE == 1) {
          float pg = (n < 512) ? E1[(size_t)vrow * 512 + n]
                               : E2[(size_t)m * 512 + (n - 512)];
          ((u16*)Cout)[(size_t)m * N + n] = f2bf(pg * fast_sigmoid(x));
        } else {
          ((float*)Cout)[(size_t)m * N + n] = x;
        }
      }
    }
  }
}

// ---------------------------------------------------------------------------
// sc[b,tl,s] = sum_d v * tanh(cwm + cm) via tanh(a+b) = 1 - 2/(E*F+1),
// E=e^{2a}, F=e^{2b} precomputed in the k_sgemm epilogues.
__global__ __launch_bounds__(256)
void k_scores(const float* __restrict__ v, const float* __restrict__ Ecwm,
              const float* __restrict__ Fcm, float* __restrict__ sc,
              int Tc, int t0)
{
  __shared__ float vs[32][68], fs[32][68], cs[32][68];
  const int b = blockIdx.x;
  const int tl0 = blockIdx.y * 32;
  const int s0 = blockIdx.z * 32;
  const int tid = threadIdx.x;
  const int tx = tid & 15, ty = tid >> 4;
  const float* srcV = v    + ((size_t)b * 320 + t0 + tl0) * 512;
  const float* srcF = Ecwm + ((size_t)b * Tc + tl0) * 512;
  const float* srcC = Fcm  + ((size_t)b * 320 + s0) * 512;
  float a00 = 0, a01 = 0, a10 = 0, a11 = 0;
  float vs0 = 0, vs1 = 0;
  for (int d0 = 0; d0 < 512; d0 += 64) {
#pragma unroll
    for (int r = 0; r < 2; ++r) {
      int f = r * 256 + tid;       // 512 f4 per array: 32 rows x 16 f4
      int row = f >> 4, qq = f & 15;
      *(float4*)&vs[row][qq * 4] = *(const float4*)(srcV + (size_t)row * 512 + d0 + qq * 4);
      *(float4*)&fs[row][qq * 4] = *(const float4*)(srcF + (size_t)row * 512 + d0 + qq * 4);
      *(float4*)&cs[row][qq * 4] = *(const float4*)(srcC + (size_t)row * 512 + d0 + qq * 4);
    }
    __syncthreads();
#pragma unroll 4
    for (int d = 0; d < 64; ++d) {
      float c0 = cs[tx][d], c1 = cs[tx + 16][d];
      float e0 = fs[ty][d], e1 = fs[ty + 16][d];
      float v0 = vs[ty][d], v1 = vs[ty + 16][d];
      vs0 += v0; vs1 += v1;
      a00 = fmaf(v0, fast_rcp(fmaf(e0, c0, 1.0f)), a00);
      a01 = fmaf(v0, fast_rcp(fmaf(e0, c1, 1.0f)), a01);
      a10 = fmaf(v1, fast_rcp(fmaf(e1, c0, 1.0f)), a10);
      a11 = fmaf(v1, fast_rcp(fmaf(e1, c1, 1.0f)), a11);
    }
    __syncthreads();
  }
  float* o = sc + (size_t)b * Tc * 320;
  o[(size_t)(tl0 + ty) * 320 + s0 + tx]           = vs0 - 2.0f * a00;
  o[(size_t)(tl0 + ty) * 320 + s0 + tx + 16]      = vs0 - 2.0f * a01;
  o[(size_t)(tl0 + ty + 16) * 320 + s0 + tx]      = vs1 - 2.0f * a10;
  o[(size_t)(tl0 + ty + 16) * 320 + s0 + tx + 16] = vs1 - 2.0f * a11;
}

// ---------------------------------------------------------------------------
// In-place softmax over last dim (320). One wave per row; grid covers rows/4.
__global__ __launch_bounds__(256)
void k_softmax(float* __restrict__ sc)
{
  int wave = threadIdx.x >> 6;
  int lane = threadIdx.x & 63;
  int row = blockIdx.x * 4 + wave;
  float* p = sc + (size_t)row * 320;
  float x[5];
  float mx = -1e30f;
#pragma unroll
  for (int j = 0; j < 5; ++j) { x[j] = p[lane + 64 * j]; mx = fmaxf(mx, x[j]); }
#pragma unroll
  for (int off = 32; off > 0; off >>= 1) mx = fmaxf(mx, __shfl_xor(mx, off));
  float s = 0.f;
#pragma unroll
  for (int j = 0; j < 5; ++j) { x[j] = fast_exp(x[j] - mx); s += x[j]; }
#pragma unroll
  for (int off = 32; off > 0; off >>= 1) s += __shfl_xor(s, off);
  float rinv = fast_rcp(s);
#pragma unroll
  for (int j = 0; j < 5; ++j) p[lane + 64 * j] = x[j] * rinv;
}

// ---------------------------------------------------------------------------
// cell[b,tl,d] = sum_s attn[b,tl,s] * v[b,s,d]; also emits cell16 (bf16).
__global__ __launch_bounds__(256)
void k_cell(const float* __restrict__ attn, const float* __restrict__ v,
            float* __restrict__ cell, u16* __restrict__ cell16, int Tc)
{
  __shared__ float As[16][32], Bs[16][64];
  const int b = blockIdx.x;
  const int m0 = blockIdx.y * 32;
  const int n0 = blockIdx.z * 64;
  const int tid = threadIdx.x;
  const float* A = attn + (size_t)b * Tc * 320;
  const float* B = v + (size_t)b * 320 * 512;
  float acc[2][4];
#pragma unroll
  for (int i = 0; i < 2; ++i)
#pragma unroll
    for (int j = 0; j < 4; ++j) acc[i][j] = 0.f;
  const int tm = (tid & 15) * 2, tn = (tid >> 4) * 4;
  for (int k0 = 0; k0 < 320; k0 += 16) {
    if (tid < 128) {
      int row = tid >> 2, q = tid & 3;          // A: 32 rows x 4 f4
      float4 x = *(const float4*)(A + (size_t)(m0 + row) * 320 + k0 + q * 4);
      As[q * 4 + 0][row] = x.x;
      As[q * 4 + 1][row] = x.y;
      As[q * 4 + 2][row] = x.z;
      As[q * 4 + 3][row] = x.w;
    }
    {
      int krow = tid >> 4, qq = tid & 15;       // B: 16 k-rows x 16 f4
      *(float4*)&Bs[krow][qq * 4] =
          *(const float4*)(B + (size_t)(k0 + krow) * 512 + n0 + qq * 4);
    }
    __syncthreads();
#pragma unroll
    for (int k = 0; k < 16; ++k) {
      float a0 = As[k][tm], a1 = As[k][tm + 1];
      float bb[4];
      *(float4*)&bb[0] = *(const float4*)&Bs[k][tn];
#pragma unroll
      for (int j = 0; j < 4; ++j) { acc[0][j] += a0 * bb[j]; acc[1][j] += a1 * bb[j]; }
    }
    __syncthreads();
  }
#pragma unroll
  for (int i = 0; i < 2; ++i) {
    size_t off = ((size_t)b * Tc + m0 + tm + i) * 512 + n0 + tn;
    float4 o = make_float4(acc[i][0], acc[i][1], acc[i][2], acc[i][3]);
    *(float4*)(cell + off) = o;
    ushort4 o16;
    o16.x = f2bf(o.x); o16.y = f2bf(o.y); o16.z = f2bf(o.z); o16.w = f2bf(o.w);
    *(ushort4*)(cell16 + off) = o16;
  }
}

// ---------------------------------------------------------------------------
// Sequential GRU; one block per (b,dir), 512 threads; Whh register-resident f16.
// Round 7: even/odd chain split (6 chains of depth 32) for fdot2 ILP.
__global__ __launch_bounds__(512)
void k_recur(const float* __restrict__ GIf, const float* __restrict__ GIb,
             const float* __restrict__ Whh_f, const float* __restrict__ Whh_b,
             const float* __restrict__ bhh_f, const float* __restrict__ bhh_b,
             float* __restrict__ out, float* __restrict__ hstate,
             int Tc, int t0, int init)
{
  const int b = blockIdx.x >> 1;
  const int dir = blockIdx.x & 1;
  const int tid = threadIdx.x;
  const int i = tid & 255;
  const int half = __builtin_amdgcn_readfirstlane(tid >> 8);  // wave-uniform
  const int lane = tid & 63;

  __shared__ float part[3][256];          // half1 partial acc (r,z,n)
  __shared__ alignas(8) __fp16 hh16[256];

  const float* Wh  = dir ? Whh_b : Whh_f;
  const float* bhh = dir ? bhh_b : bhh_f;
  const float* GI  = (dir ? GIb : GIf) + (size_t)b * Tc * 768;

  // ---- load this thread's weight slice into registers (f16 pairs) ----
  h2 wr[64], wz[64], wn[64];
  {
    const float* Wr = Wh + (size_t)i * 256 + half * 128;
    const float* Wz = Wh + (size_t)(256 + i) * 256 + half * 128;
    const float* Wn = Wh + (size_t)(512 + i) * 256 + half * 128;
#pragma unroll
    for (int qd = 0; qd < 32; ++qd) {
      float4 x = *(const float4*)(Wr + 4 * qd);
      wr[2 * qd]     = __builtin_amdgcn_cvt_pkrtz(x.x, x.y);
      wr[2 * qd + 1] = __builtin_amdgcn_cvt_pkrtz(x.z, x.w);
      float4 y = *(const float4*)(Wz + 4 * qd);
      wz[2 * qd]     = __builtin_amdgcn_cvt_pkrtz(y.x, y.y);
      wz[2 * qd + 1] = __builtin_amdgcn_cvt_pkrtz(y.z, y.w);
      float4 zv = *(const float4*)(Wn + 4 * qd);
      wn[2 * qd]     = __builtin_amdgcn_cvt_pkrtz(zv.x, zv.y);
      wn[2 * qd + 1] = __builtin_amdgcn_cvt_pkrtz(zv.z, zv.w);
    }
  }

  float br = 0.f, bz = 0.f, bn = 0.f, hown = 0.f;
  if (half == 0) {
    br = bhh[i]; bz = bhh[256 + i]; bn = bhh[512 + i];
    hown = init ? 0.f : hstate[(size_t)blockIdx.x * 256 + i];
    hh16[i] = (__fp16)hown;
  }
  float* op = out + (size_t)t0 * 32768 + (size_t)b * 512 + dir * 256 + i;
  __syncthreads();

  // distributed h: lane L holds halves 4L..4L+3 as two packed pairs
  int2 hp = *(const int2*)((const char*)hh16 + 8 * lane);

  for (int t = 0; t < Tc; ++t) {
    const float* gi = GI + (size_t)t * 768;
    float gr = 0.f, gz = 0.f, gn = 0.f;
    if (half == 0) { gr = gi[i]; gz = gi[256 + i]; gn = gi[512 + i]; }

    float ar0 = 0.f, az0 = 0.f, an0 = 0.f;
    float ar1 = 0.f, az1 = 0.f, an1 = 0.f;
    const int lbase = half * 32;
#pragma unroll
    for (int p = 0; p < 64; p += 2) {
      h2 h0 = __builtin_bit_cast(h2, __builtin_amdgcn_readlane(hp.x, lbase + (p >> 1)));
      h2 h1 = __builtin_bit_cast(h2, __builtin_amdgcn_readlane(hp.y, lbase + (p >> 1)));
      ar0 = __builtin_amdgcn_fdot2(wr[p], h0, ar0, false);
      az0 = __builtin_amdgcn_fdot2(wz[p], h0, az0, false);
      an0 = __builtin_amdgcn_fdot2(wn[p], h0, an0, false);
      ar1 = __builtin_amdgcn_fdot2(wr[p + 1], h1, ar1, false);
      az1 = __builtin_amdgcn_fdot2(wz[p + 1], h1, az1, false);
      an1 = __builtin_amdgcn_fdot2(wn[p + 1], h1, an1, false);
    }
    float ar = ar0 + ar1, az = az0 + az1, an = an0 + an1;
    if (half == 1) {
      part[0][i] = ar; part[1][i] = az; part[2][i] = an;
    }
    __syncthreads();                       // A: partials visible
    if (half == 0) {
      float r  = fast_sigmoid(gr + ar + part[0][i] + br);
      float z  = fast_sigmoid(gz + az + part[1][i] + bz);
      float nn = fast_tanh(gn + r * (an + part[2][i] + bn));
      hown = (1.f - z) * nn + z * hown;
      op[(size_t)t * 32768] = hown;        // out[t0+t, b, dir*256+i]
      hh16[i] = (__fp16)hown;
    }
    __syncthreads();                       // B: new h visible
    hp = *(const int2*)((const char*)hh16 + 8 * lane);
  }
  if (half == 0) hstate[(size_t)blockIdx.x * 256 + i] = hown;
}

// ---------------------------------------------------------------------------
extern "C" void kernel_launch(void* const* d_in, const int* in_sizes, int n_in,
                              void* d_out, int out_size, void* d_ws, size_t ws_size,
                              hipStream_t stream)
{
  const float* v     = (const float*)d_in[0];
  const float* W1    = (const float*)d_in[1];
  const float* b1    = (const float*)d_in[2];
  const float* W2    = (const float*)d_in[3];
  const float* b2    = (const float*)d_in[4];
  const float* Wg    = (const float*)d_in[5];
  const float* bg    = (const float*)d_in[6];
  const float* Wih_f = (const float*)d_in[7];
  const float* Whh_f = (const float*)d_in[8];
  const float* bih_f = (const float*)d_in[9];
  const float* bhh_f = (const float*)d_in[10];
  const float* Wih_b = (const float*)d_in[11];
  const float* Whh_b = (const float*)d_in[12];
  const float* bih_b = (const float*)d_in[13];
  const float* bhh_b = (const float*)d_in[14];
  float* out = (float*)d_out;
  float* w = (float*)d_ws;

  // Largest chunk that fits: bytes = 4*(22839296 + 233472*Tc).
  // Tc=320 -> 390 MB, 160 -> 241 MB, 64 -> 151 MB, 32 -> 121 MB.
  int Tc = 32;
  {
    const int cand[4] = {320, 160, 64, 32};
    for (int ci = 0; ci < 4; ++ci) {
      size_t need = 4ull * (22839296ull + 233472ull * (size_t)cand[ci]);
      if (need <= ws_size) { Tc = cand[ci]; break; }
    }
  }
  const int nc = 320 / Tc;

  // Workspace layout (float units)
  float* cm     = w;                                   // 10485760 (stores e^{2cm})
  float* hstate = w + 10485760;                        // 32768
  u16*  vhi     = (u16*)(w + 10518528);                // 10485760 halfs
  u16*  vlo     = (u16*)(w + 15761408);                // 10485760 halfs
  u16*  Wg16    = (u16*)(w + 21004288);                // 1048576 halfs
  u16*  Wif16   = (u16*)(w + 21528576);                // 786432 halfs
  u16*  Wib16   = (u16*)(w + 21921792);                // 786432 halfs
  u16*  W1hi    = (u16*)(w + 22315008);                // 262144 halfs
  u16*  W1lo    = (u16*)(w + 22446080);
  u16*  W2hi    = (u16*)(w + 22577152);
  u16*  W2lo    = (u16*)(w + 22708224);
  {
    size_t base = 22839296;
    float* cwm;  float* attn;  float* cell;  u16* cell16;  u16* gi16;
    cwm    = w + base;                                  base += (size_t)32768 * Tc;
    attn   = w + base;                                  base += (size_t)20480 * Tc;
    cell   = w + base;                                  base += (size_t)32768 * Tc;
    cell16 = (u16*)(w + base);                          base += (size_t)16384 * Tc;
    gi16   = (u16*)(w + base);                          base += (size_t)32768 * Tc;
    float* GIf = w + base;                              base += (size_t)49152 * Tc;
    float* GIb = w + base;

    // ---- launches ----
    k_split<<<(2621440 + 255) / 256, 256, 0, stream>>>(v, vhi, vlo, 2621440);
    k_split<<<(65536 + 255) / 256, 256, 0, stream>>>(W1, W1hi, W1lo, 65536);
    k_split<<<(65536 + 255) / 256, 256, 0, stream>>>(W2, W2hi, W2lo, 65536);
    k_cvt<<<(262144 + 255) / 256, 256, 0, stream>>>(Wg, Wg16, 262144);
    k_cvt<<<(196608 + 255) / 256, 256, 0, stream>>>(Wih_f, Wif16, 196608);
    k_cvt<<<(196608 + 255) / 256, 256, 0, stream>>>(Wih_b, Wib16, 196608);

    // cm = e^{2(v@W2^T + b2)} (split-bf16 MFMA, fp32-accurate)
    k_sgemm<1><<<dim3(160, 4), 256, 0, stream>>>(vhi, vlo, W2hi, W2lo, b2,
                                                 cm, 512, 512, 320, 0);

    for (int c = 0; c < nc; ++c) {
      const int t0 = c * Tc;
      const int Mc = 64 * Tc;
      // cwm = e^{2(v_chunk@W1^T + b1)} (split-bf16 MFMA)
      k_sgemm<1><<<dim3(Mc / 128, 4), 256, 0, stream>>>(vhi, vlo, W1hi, W1lo, b1,
                                                        cwm, 512, 512, Tc, t0);
      k_scores<<<dim3(64, Tc / 32, 10), 256, 0, stream>>>(v, cwm, cm, attn, Tc, t0);
      k_softmax<<<Mc / 4, 256, 0, stream>>>(attn);
      k_cell<<<dim3(64, Tc / 32, 8), 256, 0, stream>>>(attn, v, cell, cell16, Tc);
      // gi16 = bf16( pg * sigmoid(pg@Wg^T + bg) ), pg = [v|cell]  (bf16 MFMA)
      k_mgemm<1><<<dim3(Mc / 128, 8), 256, 0, stream>>>(vhi, 512, 1, cell16, Wg16, bg,
                                                        v, cell, gi16, 1024, 1024, Tc, t0);
      // GI_f/b = gi@Wih^T + bih  (bf16 MFMA, fp32 out)
      k_mgemm<0><<<dim3(Mc / 128, 6), 256, 0, stream>>>(gi16, 1024, 0, nullptr, Wif16, bih_f,
                                                        nullptr, nullptr, GIf, 768, 1024, Tc, t0);
      k_mgemm<0><<<dim3(Mc / 128, 6), 256, 0, stream>>>(gi16, 1024, 0, nullptr, Wib16, bih_b,
                                                        nullptr, nullptr, GIb, 768, 1024, Tc, t0);
      k_recur<<<128, 512, 0, stream>>>(GIf, GIb, Whh_f, Whh_b, bhh_f, bhh_b,
                                       out, hstate, Tc, t0, (c == 0) ? 1 : 0);
    }
  }
}

// Round 8
// 1473.952 us; speedup vs baseline: 3.6953x; 1.0609x over previous
//
#include <hip/hip_runtime.h>

typedef unsigned short u16;
typedef __fp16 h2 __attribute__((ext_vector_type(2)));
typedef __attribute__((ext_vector_type(8))) short bf16x8;   // 8 bf16 = 4 VGPRs
typedef __attribute__((ext_vector_type(4))) float f32x4;

__device__ __forceinline__ float fast_exp(float x) { return __expf(x); }
__device__ __forceinline__ float fast_rcp(float x) { return __builtin_amdgcn_rcpf(x); }
__device__ __forceinline__ float fast_tanh(float x) {
  float e = fast_exp(2.0f * x);            // 1 - 2/(e^{2x}+1), saturates correctly
  return 1.0f - 2.0f * fast_rcp(e + 1.0f);
}
__device__ __forceinline__ float fast_sigmoid(float x) {
  return fast_rcp(1.0f + fast_exp(-x));
}
__device__ __forceinline__ u16 f2bf(float x) {  // round-to-nearest-even
  unsigned u = __float_as_uint(x);
  return (u16)((u + 0x7fffu + ((u >> 16) & 1u)) >> 16);
}
__device__ __forceinline__ float bf2f(u16 u) {
  return __uint_as_float(((unsigned)u) << 16);
}
// Async global->LDS 16B: HW writes to wave-uniform LDS base + lane*16.
__device__ __forceinline__ void gload16(const u16* g, u16* l) {
  __builtin_amdgcn_global_load_lds(
      (const __attribute__((address_space(1))) unsigned int*)g,
      (__attribute__((address_space(3))) unsigned int*)l, 16, 0, 0);
}

// ---------------------------------------------------------------------------
// fp32 -> bf16 bulk convert (n4 float4-groups)
__global__ __launch_bounds__(256)
void k_cvt(const float* __restrict__ src, u16* __restrict__ dst, int n4)
{
  int i = blockIdx.x * 256 + threadIdx.x;
  if (i < n4) {
    float4 x = ((const float4*)src)[i];
    ushort4 o;
    o.x = f2bf(x.x); o.y = f2bf(x.y); o.z = f2bf(x.z); o.w = f2bf(x.w);
    ((ushort4*)dst)[i] = o;
  }
}

// ---------------------------------------------------------------------------
// fp32 -> (hi, lo) bf16 split: x ~= hi + lo, |err| ~ 2^-17 |x|.
__global__ __launch_bounds__(256)
void k_split(const float* __restrict__ src, u16* __restrict__ hi,
             u16* __restrict__ lo, int n4)
{
  int i = blockIdx.x * 256 + threadIdx.x;
  if (i < n4) {
    float4 x = ((const float4*)src)[i];
    ushort4 h, l;
    h.x = f2bf(x.x); l.x = f2bf(x.x - bf2f(h.x));
    h.y = f2bf(x.y); l.y = f2bf(x.y - bf2f(h.y));
    h.z = f2bf(x.z); l.z = f2bf(x.z - bf2f(h.z));
    h.w = f2bf(x.w); l.w = f2bf(x.w - bf2f(h.w));
    ((ushort4*)hi)[i] = h;
    ((ushort4*)lo)[i] = l;
  }
}

// ---------------------------------------------------------------------------
// Split-bf16 "fp32-accurate" MFMA GEMM for cm/cwm (3 MFMAs per fragment).
// Staging via global_load_lds (unpadded [128][32] LDS => dst = base + tid*16B).
template<int EXPOUT>
__global__ __launch_bounds__(256)
void k_sgemm(const u16* __restrict__ Ahi, const u16* __restrict__ Alo,
             const u16* __restrict__ Whi, const u16* __restrict__ Wlo,
             const float* __restrict__ bias,
             float* __restrict__ C, int N, int K, int Tc, int t0)
{
  __shared__ alignas(16) u16 Ah[128][32];
  __shared__ alignas(16) u16 Al[128][32];
  __shared__ alignas(16) u16 Bh[128][32];
  __shared__ alignas(16) u16 Bl[128][32];
  const int tid = threadIdx.x;
  const int m0 = blockIdx.x * 128;
  const int n0 = blockIdx.y * 128;
  const int wave = tid >> 6, lane = tid & 63;
  const int wm = (wave & 1) * 64, wn = (wave >> 1) * 64;

  const u16 *pAh[2], *pAl[2], *pBh[2], *pBl[2];
#pragma unroll
  for (int r = 0; r < 2; ++r) {
    int row = r * 64 + (tid >> 2);
    int gm = m0 + row;
    int ar = (gm / Tc) * 320 + t0 + gm % Tc;
    pAh[r] = Ahi + (size_t)ar * K;
    pAl[r] = Alo + (size_t)ar * K;
    int gn = n0 + row;
    pBh[r] = Whi + (size_t)gn * K;
    pBl[r] = Wlo + (size_t)gn * K;
  }

  f32x4 acc[4][4];
#pragma unroll
  for (int a = 0; a < 4; ++a)
#pragma unroll
    for (int b = 0; b < 4; ++b) acc[a][b] = (f32x4){0.f, 0.f, 0.f, 0.f};

  const int lrow = lane & 15, lq = lane >> 4;

  for (int k0 = 0; k0 < K; k0 += 32) {
    const int kk = k0 + (tid & 3) * 8;
#pragma unroll
    for (int r = 0; r < 2; ++r) {
      gload16(pAh[r] + kk, &Ah[0][0] + r * 2048 + tid * 8);
      gload16(pAl[r] + kk, &Al[0][0] + r * 2048 + tid * 8);
      gload16(pBh[r] + kk, &Bh[0][0] + r * 2048 + tid * 8);
      gload16(pBl[r] + kk, &Bl[0][0] + r * 2048 + tid * 8);
    }
    __syncthreads();
    bf16x8 avh[4], avl[4], bvh[4], bvl[4];
#pragma unroll
    for (int f = 0; f < 4; ++f) {
      avh[f] = *(const bf16x8*)&Ah[wm + f * 16 + lrow][lq * 8];
      avl[f] = *(const bf16x8*)&Al[wm + f * 16 + lrow][lq * 8];
      bvh[f] = *(const bf16x8*)&Bh[wn + f * 16 + lrow][lq * 8];
      bvl[f] = *(const bf16x8*)&Bl[wn + f * 16 + lrow][lq * 8];
    }
#pragma unroll
    for (int mf = 0; mf < 4; ++mf)
#pragma unroll
      for (int nf = 0; nf < 4; ++nf) {
        acc[mf][nf] = __builtin_amdgcn_mfma_f32_16x16x32_bf16(
            avh[mf], bvh[nf], acc[mf][nf], 0, 0, 0);
        acc[mf][nf] = __builtin_amdgcn_mfma_f32_16x16x32_bf16(
            avh[mf], bvl[nf], acc[mf][nf], 0, 0, 0);
        acc[mf][nf] = __builtin_amdgcn_mfma_f32_16x16x32_bf16(
            avl[mf], bvh[nf], acc[mf][nf], 0, 0, 0);
      }
    __syncthreads();
  }

  const int c = lane & 15, rg = lane >> 4;
#pragma unroll
  for (int mf = 0; mf < 4; ++mf) {
#pragma unroll
    for (int r = 0; r < 4; ++r) {
      int m = m0 + wm + mf * 16 + rg * 4 + r;
#pragma unroll
      for (int nf = 0; nf < 4; ++nf) {
        int n = n0 + wn + nf * 16 + c;
        float x = acc[mf][nf][r] + bias[n];
        C[(size_t)m * N + n] = EXPOUT ? fast_exp(2.0f * x) : x;
      }
    }
  }
}

// ---------------------------------------------------------------------------
// bf16 MFMA GEMM (gate paths), global_load_lds staging.
// MODE 0: fp32 C = acc + bias.  MODE 1: bf16 C = pg*sigmoid(acc+bias),
// pg = [E1(v,fp32,row-mapped) | E2(cell,fp32)].
template<int MODE>
__global__ __launch_bounds__(256)
void k_mgemm(const u16* __restrict__ A1, int K1, int map1,
             const u16* __restrict__ A2,
             const u16* __restrict__ W16, const float* __restrict__ bias,
             const float* __restrict__ E1, const float* __restrict__ E2,
             void* __restrict__ Cout, int N, int K, int Tc, int t0)
{
  __shared__ alignas(16) u16 As[128][32];
  __shared__ alignas(16) u16 Bs[128][32];
  const int tid = threadIdx.x;
  const int m0 = blockIdx.x * 128;
  const int n0 = blockIdx.y * 128;
  const int wave = tid >> 6, lane = tid & 63;
  const int wm = (wave & 1) * 64, wn = (wave >> 1) * 64;
  const int K2 = K - K1;

  const u16* pA1r[2];
  const u16* pA2r[2];
  const u16* pWr[2];
#pragma unroll
  for (int r = 0; r < 2; ++r) {
    int row = r * 64 + (tid >> 2);
    int gm = m0 + row;
    int ar1 = map1 ? ((gm / Tc) * 320 + t0 + gm % Tc) : gm;
    pA1r[r] = A1 + (size_t)ar1 * K1;
    pA2r[r] = A2 ? (A2 + (size_t)gm * K2) : pA1r[r];   // A2 never mapped
    pWr[r] = W16 + (size_t)(n0 + row) * K;
  }

  f32x4 acc[4][4];
#pragma unroll
  for (int a = 0; a < 4; ++a)
#pragma unroll
    for (int b = 0; b < 4; ++b) acc[a][b] = (f32x4){0.f, 0.f, 0.f, 0.f};

  const int lrow = lane & 15, lq = lane >> 4;

  for (int k0 = 0; k0 < K; k0 += 32) {
    const int kk = k0 + (tid & 3) * 8;
#pragma unroll
    for (int r = 0; r < 2; ++r) {
      const u16* s = (kk < K1) ? (pA1r[r] + kk) : (pA2r[r] + (kk - K1));
      gload16(s, &As[0][0] + r * 2048 + tid * 8);
      gload16(pWr[r] + kk, &Bs[0][0] + r * 2048 + tid * 8);
    }
    __syncthreads();
    bf16x8 av[4], bv[4];
#pragma unroll
    for (int f = 0; f < 4; ++f) {
      av[f] = *(const bf16x8*)&As[wm + f * 16 + lrow][lq * 8];
      bv[f] = *(const bf16x8*)&Bs[wn + f * 16 + lrow][lq * 8];
    }
#pragma unroll
    for (int mf = 0; mf < 4; ++mf)
#pragma unroll
      for (int nf = 0; nf < 4; ++nf)
        acc[mf][nf] = __builtin_amdgcn_mfma_f32_16x16x32_bf16(
            av[mf], bv[nf], acc[mf][nf], 0, 0, 0);
    __syncthreads();
  }

  // epilogue: lane holds C[m=rg*4+r][n=c] per fragment
  const int c = lane & 15, rg = lane >> 4;
#pragma unroll
  for (int mf = 0; mf < 4; ++mf) {
#pragma unroll
    for (int r = 0; r < 4; ++r) {
      int m = m0 + wm + mf * 16 + rg * 4 + r;
      int vrow = map1 ? ((m / Tc) * 320 + t0 + m % Tc) : m;
#pragma unroll
      for (int nf = 0; nf < 4; ++nf) {
        int n = n0 + wn + nf * 16 + c;
        float x = acc[mf][nf][r] + bias[n];
        if (MODE == 1) {
          float pg = (n < 512) ? E1[(size_t)vrow * 512 + n]
                               : E2[(size_t)m * 512 + (n - 512)];
          ((u16*)Cout)[(size_t)m * N + n] = f2bf(pg * fast_sigmoid(x));
        } else {
          ((float*)Cout)[(size_t)m * N + n] = x;
        }
      }
    }
  }
}

// ---------------------------------------------------------------------------
// sc[b,tl,s] = sum_d v * tanh(cwm + cm) via tanh(a+b) = 1 - 2/(E*F+1),
// E=e^{2a}, F=e^{2b} precomputed in the k_sgemm epilogues.
__global__ __launch_bounds__(256)
void k_scores(const float* __restrict__ v, const float* __restrict__ Ecwm,
              const float* __restrict__ Fcm, float* __restrict__ sc,
              int Tc, int t0)
{
  __shared__ float vs[32][68], fs[32][68], cs[32][68];
  const int b = blockIdx.x;
  const int tl0 = blockIdx.y * 32;
  const int s0 = blockIdx.z * 32;
  const int tid = threadIdx.x;
  const int tx = tid & 15, ty = tid >> 4;
  const float* srcV = v    + ((size_t)b * 320 + t0 + tl0) * 512;
  const float* srcF = Ecwm + ((size_t)b * Tc + tl0) * 512;
  const float* srcC = Fcm  + ((size_t)b * 320 + s0) * 512;
  float a00 = 0, a01 = 0, a10 = 0, a11 = 0;
  float vs0 = 0, vs1 = 0;
  for (int d0 = 0; d0 < 512; d0 += 64) {
#pragma unroll
    for (int r = 0; r < 2; ++r) {
      int f = r * 256 + tid;       // 512 f4 per array: 32 rows x 16 f4
      int row = f >> 4, qq = f & 15;
      *(float4*)&vs[row][qq * 4] = *(const float4*)(srcV + (size_t)row * 512 + d0 + qq * 4);
      *(float4*)&fs[row][qq * 4] = *(const float4*)(srcF + (size_t)row * 512 + d0 + qq * 4);
      *(float4*)&cs[row][qq * 4] = *(const float4*)(srcC + (size_t)row * 512 + d0 + qq * 4);
    }
    __syncthreads();
#pragma unroll 4
    for (int d = 0; d < 64; ++d) {
      float c0 = cs[tx][d], c1 = cs[tx + 16][d];
      float e0 = fs[ty][d], e1 = fs[ty + 16][d];
      float v0 = vs[ty][d], v1 = vs[ty + 16][d];
      vs0 += v0; vs1 += v1;
      a00 = fmaf(v0, fast_rcp(fmaf(e0, c0, 1.0f)), a00);
      a01 = fmaf(v0, fast_rcp(fmaf(e0, c1, 1.0f)), a01);
      a10 = fmaf(v1, fast_rcp(fmaf(e1, c0, 1.0f)), a10);
      a11 = fmaf(v1, fast_rcp(fmaf(e1, c1, 1.0f)), a11);
    }
    __syncthreads();
  }
  float* o = sc + (size_t)b * Tc * 320;
  o[(size_t)(tl0 + ty) * 320 + s0 + tx]           = vs0 - 2.0f * a00;
  o[(size_t)(tl0 + ty) * 320 + s0 + tx + 16]      = vs0 - 2.0f * a01;
  o[(size_t)(tl0 + ty + 16) * 320 + s0 + tx]      = vs1 - 2.0f * a10;
  o[(size_t)(tl0 + ty + 16) * 320 + s0 + tx + 16] = vs1 - 2.0f * a11;
}

// ---------------------------------------------------------------------------
// In-place softmax over last dim (320). One wave per row; grid covers rows/4.
__global__ __launch_bounds__(256)
void k_softmax(float* __restrict__ sc)
{
  int wave = threadIdx.x >> 6;
  int lane = threadIdx.x & 63;
  int row = blockIdx.x * 4 + wave;
  float* p = sc + (size_t)row * 320;
  float x[5];
  float mx = -1e30f;
#pragma unroll
  for (int j = 0; j < 5; ++j) { x[j] = p[lane + 64 * j]; mx = fmaxf(mx, x[j]); }
#pragma unroll
  for (int off = 32; off > 0; off >>= 1) mx = fmaxf(mx, __shfl_xor(mx, off));
  float s = 0.f;
#pragma unroll
  for (int j = 0; j < 5; ++j) { x[j] = fast_exp(x[j] - mx); s += x[j]; }
#pragma unroll
  for (int off = 32; off > 0; off >>= 1) s += __shfl_xor(s, off);
  float rinv = fast_rcp(s);
#pragma unroll
  for (int j = 0; j < 5; ++j) p[lane + 64 * j] = x[j] * rinv;
}

// ---------------------------------------------------------------------------
// cell[b,tl,d] = sum_s attn[b,tl,s] * v[b,s,d]; also emits cell16 (bf16).
__global__ __launch_bounds__(256)
void k_cell(const float* __restrict__ attn, const float* __restrict__ v,
            float* __restrict__ cell, u16* __restrict__ cell16, int Tc)
{
  __shared__ float As[16][32], Bs[16][64];
  const int b = blockIdx.x;
  const int m0 = blockIdx.y * 32;
  const int n0 = blockIdx.z * 64;
  const int tid = threadIdx.x;
  const float* A = attn + (size_t)b * Tc * 320;
  const float* B = v + (size_t)b * 320 * 512;
  float acc[2][4];
#pragma unroll
  for (int i = 0; i < 2; ++i)
#pragma unroll
    for (int j = 0; j < 4; ++j) acc[i][j] = 0.f;
  const int tm = (tid & 15) * 2, tn = (tid >> 4) * 4;
  for (int k0 = 0; k0 < 320; k0 += 16) {
    if (tid < 128) {
      int row = tid >> 2, q = tid & 3;          // A: 32 rows x 4 f4
      float4 x = *(const float4*)(A + (size_t)(m0 + row) * 320 + k0 + q * 4);
      As[q * 4 + 0][row] = x.x;
      As[q * 4 + 1][row] = x.y;
      As[q * 4 + 2][row] = x.z;
      As[q * 4 + 3][row] = x.w;
    }
    {
      int krow = tid >> 4, qq = tid & 15;       // B: 16 k-rows x 16 f4
      *(float4*)&Bs[krow][qq * 4] =
          *(const float4*)(B + (size_t)(k0 + krow) * 512 + n0 + qq * 4);
    }
    __syncthreads();
#pragma unroll
    for (int k = 0; k < 16; ++k) {
      float a0 = As[k][tm], a1 = As[k][tm + 1];
      float bb[4];
      *(float4*)&bb[0] = *(const float4*)&Bs[k][tn];
#pragma unroll
      for (int j = 0; j < 4; ++j) { acc[0][j] += a0 * bb[j]; acc[1][j] += a1 * bb[j]; }
    }
    __syncthreads();
  }
#pragma unroll
  for (int i = 0; i < 2; ++i) {
    size_t off = ((size_t)b * Tc + m0 + tm + i) * 512 + n0 + tn;
    float4 o = make_float4(acc[i][0], acc[i][1], acc[i][2], acc[i][3]);
    *(float4*)(cell + off) = o;
    ushort4 o16;
    o16.x = f2bf(o.x); o16.y = f2bf(o.y); o16.z = f2bf(o.z); o16.w = f2bf(o.w);
    *(ushort4*)(cell16 + off) = o16;
  }
}

// ---------------------------------------------------------------------------
// Sequential GRU v3. One block per (b,dir), 1024 threads: thread=(i=tid>>2,
// kq=tid&3). Weights 96 VGPRs/thread (fits 128 cap at 16 waves/CU). Partial
// dots for one i live in a lane QUAD -> in-wave shfl_xor reduction (no LDS
// partials, ONE barrier/step). h broadcast via ds_read_b128 of a
// double-buffered fp16 h (LDS pipe, off the VALU critical path).
__global__ __launch_bounds__(1024)
void k_recur(const float* __restrict__ GIf, const float* __restrict__ GIb,
             const float* __restrict__ Whh_f, const float* __restrict__ Whh_b,
             const float* __restrict__ bhh_f, const float* __restrict__ bhh_b,
             float* __restrict__ out, float* __restrict__ hstate,
             int Tc, int t0, int init)
{
  const int b = blockIdx.x >> 1;
  const int dir = blockIdx.x & 1;
  const int tid = threadIdx.x;
  const int i = tid >> 2;
  const int kq = tid & 3;
  const bool head = (kq == 0);

  __shared__ alignas(16) __fp16 hbuf[2][256];

  const float* Wh  = dir ? Whh_b : Whh_f;
  const float* bhh = dir ? bhh_b : bhh_f;
  const float* GI  = (dir ? GIb : GIf) + (size_t)b * Tc * 768;

  // ---- weight slice: rows (i, 256+i, 512+i), k in [kq*64, kq*64+64) ----
  h2 wr[32], wz[32], wn[32];
  {
    const float* Wr = Wh + (size_t)i * 256 + kq * 64;
    const float* Wz = Wh + (size_t)(256 + i) * 256 + kq * 64;
    const float* Wn = Wh + (size_t)(512 + i) * 256 + kq * 64;
#pragma unroll
    for (int qd = 0; qd < 16; ++qd) {
      float4 x = *(const float4*)(Wr + 4 * qd);
      wr[2 * qd]     = __builtin_amdgcn_cvt_pkrtz(x.x, x.y);
      wr[2 * qd + 1] = __builtin_amdgcn_cvt_pkrtz(x.z, x.w);
      float4 y = *(const float4*)(Wz + 4 * qd);
      wz[2 * qd]     = __builtin_amdgcn_cvt_pkrtz(y.x, y.y);
      wz[2 * qd + 1] = __builtin_amdgcn_cvt_pkrtz(y.z, y.w);
      float4 zv = *(const float4*)(Wn + 4 * qd);
      wn[2 * qd]     = __builtin_amdgcn_cvt_pkrtz(zv.x, zv.y);
      wn[2 * qd + 1] = __builtin_amdgcn_cvt_pkrtz(zv.z, zv.w);
    }
  }

  float br = 0.f, bz = 0.f, bn = 0.f, hown = 0.f;
  if (head) {
    br = bhh[i]; bz = bhh[256 + i]; bn = bhh[512 + i];
    hown = init ? 0.f : hstate[(size_t)blockIdx.x * 256 + i];
    hbuf[0][i] = (__fp16)hown;
  }
  float* op = out + (size_t)t0 * 32768 + (size_t)b * 512 + dir * 256 + i;
  __syncthreads();

  for (int t = 0; t < Tc; ++t) {
    const int cur = t & 1;
    const float* gi = GI + (size_t)t * 768;
    float gr = 0.f, gz = 0.f, gn = 0.f;
    if (head) { gr = gi[i]; gz = gi[256 + i]; gn = gi[512 + i]; }

    float ar = 0.f, az = 0.f, an = 0.f;
    const int4* hp = (const int4*)(&hbuf[cur][kq * 64]);   // 128B-aligned
#pragma unroll
    for (int j = 0; j < 8; ++j) {
      int4 hv = hp[j];                                     // 8 h values
      h2 h0 = __builtin_bit_cast(h2, hv.x);
      h2 h1 = __builtin_bit_cast(h2, hv.y);
      h2 h2v = __builtin_bit_cast(h2, hv.z);
      h2 h3 = __builtin_bit_cast(h2, hv.w);
      ar = __builtin_amdgcn_fdot2(wr[4 * j + 0], h0, ar, false);
      az = __builtin_amdgcn_fdot2(wz[4 * j + 0], h0, az, false);
      an = __builtin_amdgcn_fdot2(wn[4 * j + 0], h0, an, false);
      ar = __builtin_amdgcn_fdot2(wr[4 * j + 1], h1, ar, false);
      az = __builtin_amdgcn_fdot2(wz[4 * j + 1], h1, az, false);
      an = __builtin_amdgcn_fdot2(wn[4 * j + 1], h1, an, false);
      ar = __builtin_amdgcn_fdot2(wr[4 * j + 2], h2v, ar, false);
      az = __builtin_amdgcn_fdot2(wz[4 * j + 2], h2v, az, false);
      an = __builtin_amdgcn_fdot2(wn[4 * j + 2], h2v, an, false);
      ar = __builtin_amdgcn_fdot2(wr[4 * j + 3], h3, ar, false);
      az = __builtin_amdgcn_fdot2(wz[4 * j + 3], h3, az, false);
      an = __builtin_amdgcn_fdot2(wn[4 * j + 3], h3, an, false);
    }
    // in-quad reduction (lanes differing in bits 0-1 hold the 4 k-quarters)
    ar += __shfl_xor(ar, 1); ar += __shfl_xor(ar, 2);
    az += __shfl_xor(az, 1); az += __shfl_xor(az, 2);
    an += __shfl_xor(an, 1); an += __shfl_xor(an, 2);

    if (head) {
      float r  = fast_sigmoid(gr + ar + br);
      float z  = fast_sigmoid(gz + az + bz);
      float nn = fast_tanh(gn + r * (an + bn));
      hown = (1.f - z) * nn + z * hown;
      op[(size_t)t * 32768] = hown;        // out[t0+t, b, dir*256+i]
      hbuf[cur ^ 1][i] = (__fp16)hown;
    }
    __syncthreads();                       // h(t+1) visible; old buf free
  }
  if (head) hstate[(size_t)blockIdx.x * 256 + i] = hown;
}

// ---------------------------------------------------------------------------
extern "C" void kernel_launch(void* const* d_in, const int* in_sizes, int n_in,
                              void* d_out, int out_size, void* d_ws, size_t ws_size,
                              hipStream_t stream)
{
  const float* v     = (const float*)d_in[0];
  const float* W1    = (const float*)d_in[1];
  const float* b1    = (const float*)d_in[2];
  const float* W2    = (const float*)d_in[3];
  const float* b2    = (const float*)d_in[4];
  const float* Wg    = (const float*)d_in[5];
  const float* bg    = (const float*)d_in[6];
  const float* Wih_f = (const float*)d_in[7];
  const float* Whh_f = (const float*)d_in[8];
  const float* bih_f = (const float*)d_in[9];
  const float* bhh_f = (const float*)d_in[10];
  const float* Wih_b = (const float*)d_in[11];
  const float* Whh_b = (const float*)d_in[12];
  const float* bih_b = (const float*)d_in[13];
  const float* bhh_b = (const float*)d_in[14];
  float* out = (float*)d_out;
  float* w = (float*)d_ws;

  // Largest chunk that fits: bytes = 4*(22839296 + 233472*Tc).
  int Tc = 32;
  {
    const int cand[4] = {320, 160, 64, 32};
    for (int ci = 0; ci < 4; ++ci) {
      size_t need = 4ull * (22839296ull + 233472ull * (size_t)cand[ci]);
      if (need <= ws_size) { Tc = cand[ci]; break; }
    }
  }
  const int nc = 320 / Tc;

  // Workspace layout (float units)
  float* cm     = w;                                   // 10485760 (stores e^{2cm})
  float* hstate = w + 10485760;                        // 32768
  u16*  vhi     = (u16*)(w + 10518528);                // 10485760 halfs
  u16*  vlo     = (u16*)(w + 15761408);                // 10485760 halfs
  u16*  Wg16    = (u16*)(w + 21004288);                // 1048576 halfs
  u16*  Wif16   = (u16*)(w + 21528576);                // 786432 halfs
  u16*  Wib16   = (u16*)(w + 21921792);                // 786432 halfs
  u16*  W1hi    = (u16*)(w + 22315008);                // 262144 halfs
  u16*  W1lo    = (u16*)(w + 22446080);
  u16*  W2hi    = (u16*)(w + 22577152);
  u16*  W2lo    = (u16*)(w + 22708224);
  {
    size_t base = 22839296;
    float* cwm;  float* attn;  float* cell;  u16* cell16;  u16* gi16;
    cwm    = w + base;                                  base += (size_t)32768 * Tc;
    attn   = w + base;                                  base += (size_t)20480 * Tc;
    cell   = w + base;                                  base += (size_t)32768 * Tc;
    cell16 = (u16*)(w + base);                          base += (size_t)16384 * Tc;
    gi16   = (u16*)(w + base);                          base += (size_t)32768 * Tc;
    float* GIf = w + base;                              base += (size_t)49152 * Tc;
    float* GIb = w + base;

    // ---- launches ----
    k_split<<<(2621440 + 255) / 256, 256, 0, stream>>>(v, vhi, vlo, 2621440);
    k_split<<<(65536 + 255) / 256, 256, 0, stream>>>(W1, W1hi, W1lo, 65536);
    k_split<<<(65536 + 255) / 256, 256, 0, stream>>>(W2, W2hi, W2lo, 65536);
    k_cvt<<<(262144 + 255) / 256, 256, 0, stream>>>(Wg, Wg16, 262144);
    k_cvt<<<(196608 + 255) / 256, 256, 0, stream>>>(Wih_f, Wif16, 196608);
    k_cvt<<<(196608 + 255) / 256, 256, 0, stream>>>(Wih_b, Wib16, 196608);

    // cm = e^{2(v@W2^T + b2)} (split-bf16 MFMA, fp32-accurate)
    k_sgemm<1><<<dim3(160, 4), 256, 0, stream>>>(vhi, vlo, W2hi, W2lo, b2,
                                                 cm, 512, 512, 320, 0);

    for (int c = 0; c < nc; ++c) {
      const int t0 = c * Tc;
      const int Mc = 64 * Tc;
      // cwm = e^{2(v_chunk@W1^T + b1)} (split-bf16 MFMA)
      k_sgemm<1><<<dim3(Mc / 128, 4), 256, 0, stream>>>(vhi, vlo, W1hi, W1lo, b1,
                                                        cwm, 512, 512, Tc, t0);
      k_scores<<<dim3(64, Tc / 32, 10), 256, 0, stream>>>(v, cwm, cm, attn, Tc, t0);
      k_softmax<<<Mc / 4, 256, 0, stream>>>(attn);
      k_cell<<<dim3(64, Tc / 32, 8), 256, 0, stream>>>(attn, v, cell, cell16, Tc);
      // gi16 = bf16( pg * sigmoid(pg@Wg^T + bg) ), pg = [v|cell]  (bf16 MFMA)
      k_mgemm<1><<<dim3(Mc / 128, 8), 256, 0, stream>>>(vhi, 512, 1, cell16, Wg16, bg,
                                                        v, cell, gi16, 1024, 1024, Tc, t0);
      // GI_f/b = gi@Wih^T + bih  (bf16 MFMA, fp32 out)
      k_mgemm<0><<<dim3(Mc / 128, 6), 256, 0, stream>>>(gi16, 1024, 0, nullptr, Wif16, bih_f,
                                                        nullptr, nullptr, GIf, 768, 1024, Tc, t0);
      k_mgemm<0><<<dim3(Mc / 128, 6), 256, 0, stream>>>(gi16, 1024, 0, nullptr, Wib16, bih_b,
                                                        nullptr, nullptr, GIb, 768, 1024, Tc, t0);
      k_recur<<<128, 1024, 0, stream>>>(GIf, GIb, Whh_f, Whh_b, bhh_f, bhh_b,
                                        out, hstate, Tc, t0, (c == 0) ? 1 : 0);
    }
  }
}